// Round 6
// baseline (302.416 us; speedup 1.0000x reference)
//
#include <hip/hip_runtime.h>
#include <cstdint>
#include <cstddef>

// MHA: out = softmax_causal((XqWq^T+bq)(XkWk^T+bk)^T / 8) (XvWv^T+bv) Wo^T + bo
// B=4 S=2048 D=1024 H=16 dk=64. bf16 MFMA, fp32 accum. Softmax in exp2 domain:
// Q projection pre-scaled by 0.125*log2(e).
// ws: [0,16M) Xq->Vp ; [16M,32M) Xk->Xattn ; [32M,48M) Xv->Vt ;
// [48M,56M) weights bf16 ; [56M,72M) Qp ; [72M,88M) Kp.

typedef __attribute__((ext_vector_type(8))) short bf16x8;
typedef __attribute__((ext_vector_type(4))) float f32x4;
typedef __attribute__((ext_vector_type(16))) float f32x16;

__device__ __forceinline__ unsigned short f2bf(float f) {
  union { float f; unsigned u; } x; x.f = f;
  unsigned r = x.u + 0x7FFFu + ((x.u >> 16) & 1u);   // RNE
  return (unsigned short)(r >> 16);
}

__device__ __forceinline__ unsigned cvtpk_bf16(float lo, float hi) {
  unsigned r;
  asm("v_cvt_pk_bf16_f32 %0, %1, %2" : "=v"(r) : "v"(lo), "v"(hi));
  return r;
}

__device__ __forceinline__ f32x16 mfma32(bf16x8 a, bf16x8 b, f32x16 c) {
  return __builtin_amdgcn_mfma_f32_32x32x16_bf16(a, b, c, 0, 0, 0);
}

__device__ __forceinline__ void gld16(unsigned short* lds, const unsigned short* g) {
  __builtin_amdgcn_global_load_lds(
      (const __attribute__((address_space(1))) unsigned int*)g,
      (__attribute__((address_space(3))) unsigned int*)lds, 16, 0, 0);
}

// ---------------- fp32 -> bf16 cast ----------------
__global__ __launch_bounds__(256) void cast_bf16(const float* __restrict__ src,
                                                 unsigned short* __restrict__ dst, int n4) {
  const int i = blockIdx.x * 256 + threadIdx.x;
  if (i >= n4) return;
  const float4 f = ((const float4*)src)[i];
  ushort4 o;
  o.x = f2bf(f.x); o.y = f2bf(f.y); o.z = f2bf(f.z); o.w = f2bf(f.w);
  ((ushort4*)dst)[i] = o;
}

// ---------------- GEMM: C[m,n] = sum_k A[m,k]*W[n,k] + bias[n] ----------------
template <bool F32OUT, bool SCALEQ>
__global__ __launch_bounds__(256)
void gemm_bt(const unsigned short* __restrict__ A,
             const unsigned short* __restrict__ Bw,
             const float* __restrict__ bias,
             unsigned short* __restrict__ Cb,
             float* __restrict__ Cf,
             int M, int N, int K) {
  __shared__ unsigned short As[128 * 32];
  __shared__ unsigned short Bs[128 * 32];
  const int tid = threadIdx.x;
  const int lane = tid & 63;
  const int w = tid >> 6;
  const int wm = (w >> 1) * 64;
  const int wn = (w & 1) * 64;
  const int m0 = blockIdx.y * 128;
  const int n0 = blockIdx.x * 128;
  const int l15 = lane & 15, l4 = lane >> 4;

  f32x4 acc[4][4] = {};

  const int c0 = tid, c1 = 256 + tid;
  const int r0 = c0 >> 2, kc0 = (c0 & 3) * 8;
  const int r1 = c1 >> 2, kc1 = (c1 & 3) * 8;

  for (int k0 = 0; k0 < K; k0 += 32) {
    __syncthreads();
    gld16(&As[c0 * 8], &A[(size_t)(m0 + r0) * K + k0 + kc0]);
    gld16(&As[c1 * 8], &A[(size_t)(m0 + r1) * K + k0 + kc1]);
    gld16(&Bs[c0 * 8], &Bw[(size_t)(n0 + r0) * K + k0 + kc0]);
    gld16(&Bs[c1 * 8], &Bw[(size_t)(n0 + r1) * K + k0 + kc1]);
    __syncthreads();

    bf16x8 af[4], bfr[4];
#pragma unroll
    for (int m = 0; m < 4; ++m)
      af[m] = *(const bf16x8*)&As[(wm + m * 16 + l15) * 32 + l4 * 8];
#pragma unroll
    for (int n = 0; n < 4; ++n)
      bfr[n] = *(const bf16x8*)&Bs[(wn + n * 16 + l15) * 32 + l4 * 8];
#pragma unroll
    for (int m = 0; m < 4; ++m)
#pragma unroll
      for (int n = 0; n < 4; ++n)
        acc[m][n] = __builtin_amdgcn_mfma_f32_16x16x32_bf16(af[m], bfr[n], acc[m][n], 0, 0, 0);
  }

  const int crow = l4 * 4;
#pragma unroll
  for (int m = 0; m < 4; ++m) {
#pragma unroll
    for (int n = 0; n < 4; ++n) {
      const int col = n0 + wn + n * 16 + l15;
      const float bv_ = bias[col];
#pragma unroll
      for (int j = 0; j < 4; ++j) {
        const int row = m0 + wm + m * 16 + crow + j;
        float v = acc[m][n][j] + bv_;
        if constexpr (SCALEQ) v *= 0.125f * 1.44269504f;  // 1/sqrt(dk) * log2(e)
        if constexpr (F32OUT) Cf[(size_t)row * N + col] = v;
        else                  Cb[(size_t)row * N + col] = f2bf(v);
      }
    }
  }
}

// ---------------- V transpose: [b,s,h*64+d] -> [(b*16+h)*64+d, s] ----------------
__global__ __launch_bounds__(256)
void transpose_v(const unsigned short* __restrict__ Vp, unsigned short* __restrict__ Vt) {
  constexpr int S = 2048, Dm = 1024;
  __shared__ __align__(16) unsigned short t[64][72];
  const int bh = blockIdx.x, b = bh >> 4, h = bh & 15;
  const int s0 = blockIdx.y * 64;
  const int tid = threadIdx.x;
#pragma unroll
  for (int r = 0; r < 2; ++r) {
    const int c = r * 256 + tid;
    const int sl = c >> 3, d8 = (c & 7) * 8;
    *(bf16x8*)&t[sl][d8] =
        *(const bf16x8*)&Vp[(size_t)(b * S + s0 + sl) * Dm + h * 64 + d8];
  }
  __syncthreads();
#pragma unroll
  for (int r = 0; r < 2; ++r) {
    const int c = r * 256 + tid;
    const int dl = c >> 3, s8 = (c & 7) * 8;
    bf16x8 ov;
#pragma unroll
    for (int jj = 0; jj < 8; ++jj) ov[jj] = t[s8 + jj][dl];
    *(bf16x8*)&Vt[(size_t)(bh * 64 + dl) * S + s0 + s8] = ov;
  }
}

// ---------------- flash attention, causal, 1 wave per 32-row q-block ----------------
// Swapped QK^T (col=q lane-local softmax), O^T via A=V^T. KVBLK=32.
// K register-prefetch (ping-pong kA/kB), V issued at body start. exp2 domain.
// Grid: 4096 flat 1-wave blocks, XCD-locality swizzle: XCD c (= wgid&7, blockIdx
// round-robins XCDs) owns bh in [8c, 8c+8) -> per-XCD K/V working set ~4MB = L2.
// Within an XCD: qb descending (longest first), bh inner.
__global__ __launch_bounds__(64)
void attn_fwd32p(const unsigned short* __restrict__ Qp,   // [B*S,1024] bf16 (scaled)
                 const unsigned short* __restrict__ Kp,   // [B*S,1024] bf16
                 const unsigned short* __restrict__ Vt,   // [(b*16+h)*64+d, S] bf16
                 unsigned short* __restrict__ Xo) {       // [B*S,1024] bf16
  constexpr int S = 2048, Dm = 1024;
  const int wgid = blockIdx.x;
  const int xcd = wgid & 7;
  const int idx = wgid >> 3;          // 0..511
  const int bh = xcd * 8 + (idx & 7); // 8 heads per XCD
  const int b = bh >> 4, h = bh & 15;
  const int qb = 63 - (idx >> 3);     // longest q-blocks first within the XCD
  const int lane = threadIdx.x & 63;
  const int l31 = lane & 31, hi = lane >> 5;
  const int qrow = qb * 32 + l31;
  const int nt = qb + 1;              // KV tiles of 32; last one masked

  // Q B-frags: col=q=l31, k(d)=c*16+hi*8
  const unsigned short* qptr = Qp + (size_t)(b * S + qrow) * Dm + h * 64 + hi * 8;
  bf16x8 qf[4];
#pragma unroll
  for (int c = 0; c < 4; ++c) qf[c] = *(const bf16x8*)(qptr + c * 16);

  const unsigned short* kbase = Kp + (size_t)(b * S) * Dm + h * 64 + hi * 8;
  const unsigned short* vr0 = Vt + (size_t)(bh * 64 + l31) * S + hi * 8;
  const unsigned short* vr1 = vr0 + (size_t)32 * S;

  f32x16 ot0 = {}, ot1 = {};   // O^T: rows d (0-31 / 32-63), col q=l31
  float m = -1e30f, l = 0.f;

  auto loadK = [&](bf16x8 (&kr)[4], int t) {
    const unsigned short* krow = kbase + (size_t)(t * 32 + l31) * Dm;
#pragma unroll
    for (int c = 0; c < 4; ++c) kr[c] = *(const bf16x8*)(krow + c * 16);
  };

  auto body = [&](bf16x8 (&kr)[4], int t) {
    const int kv0 = t * 32;
    // V loads issued early; consumed after softmax (~600cy later)
    const bf16x8 vf0a = *(const bf16x8*)(vr0 + kv0);
    const bf16x8 vf0b = *(const bf16x8*)(vr0 + kv0 + 16);
    const bf16x8 vf1a = *(const bf16x8*)(vr1 + kv0);
    const bf16x8 vf1b = *(const bf16x8*)(vr1 + kv0 + 16);
    // S^T = K · Q  (rows kv, col q)
    f32x16 ts = {};
#pragma unroll
    for (int c = 0; c < 4; ++c) ts = mfma32(kr[c], qf[c], ts);
    if (t == nt - 1) {   // diagonal tile
#pragma unroll
      for (int r = 0; r < 16; ++r) {
        const int kvp = kv0 + (r & 3) + 8 * (r >> 2) + 4 * hi;
        if (kvp > qrow) ts[r] = -1e9f;
      }
    }
    // row max: lane-local + 1 cross-half shfl
    float pmax = ts[0];
#pragma unroll
    for (int r = 1; r < 16; ++r) pmax = fmaxf(pmax, ts[r]);
    pmax = fmaxf(pmax, __shfl_xor(pmax, 32));
    // deferred rescale (T13; log2 units)
    if (__any(pmax > m + 11.5f)) {
      const float mn = (pmax > m + 11.5f) ? pmax : m;
      const float fct = __builtin_amdgcn_exp2f(m - mn);
      m = mn; l *= fct;
#pragma unroll
      for (int r = 0; r < 16; ++r) { ot0[r] *= fct; ot1[r] *= fct; }
    }
    // p = 2^(s-m), row-sum
    float p[16], ls = 0.f;
#pragma unroll
    for (int r = 0; r < 16; ++r) {
      p[r] = __builtin_amdgcn_exp2f(ts[r] - m);
      ls += p[r];
    }
    ls += __shfl_xor(ls, 32);
    l += ls;
    // pack bf16 pairs + cross-half exchange -> P^T B-frags (k=kv)
    unsigned ua[8];
#pragma unroll
    for (int i = 0; i < 8; ++i) ua[i] = cvtpk_bf16(p[2 * i], p[2 * i + 1]);
    union FR { bf16x8 v; unsigned u[4]; } fr0, fr1;
    {
      unsigned sa = hi ? ua[0] : ua[2], sb = hi ? ua[1] : ua[3];
      unsigned xa = __shfl_xor(sa, 32), xb = __shfl_xor(sb, 32);
      fr0.u[0] = hi ? xa : ua[0]; fr0.u[1] = hi ? xb : ua[1];
      fr0.u[2] = hi ? ua[2] : xa; fr0.u[3] = hi ? ua[3] : xb;
      unsigned sc = hi ? ua[4] : ua[6], sd = hi ? ua[5] : ua[7];
      unsigned xc = __shfl_xor(sc, 32), xd = __shfl_xor(sd, 32);
      fr1.u[0] = hi ? xc : ua[4]; fr1.u[1] = hi ? xd : ua[5];
      fr1.u[2] = hi ? ua[6] : xc; fr1.u[3] = hi ? ua[7] : xd;
    }
    // O^T += V^T · P^T
    ot0 = mfma32(vf0a, fr0.v, ot0);
    ot0 = mfma32(vf0b, fr1.v, ot0);
    ot1 = mfma32(vf1a, fr0.v, ot1);
    ot1 = mfma32(vf1b, fr1.v, ot1);
  };

  // ping-pong K prefetch (named sets, static indexing)
  bf16x8 kA[4], kB[4];
  loadK(kA, 0);
  int t = 0;
  for (; t + 2 <= nt; t += 2) {
    loadK(kB, t + 1);
    body(kA, t);
    if (t + 2 < nt) loadK(kA, t + 2);
    body(kB, t + 1);
  }
  if (t < nt) body(kA, t);

  // epilogue: normalize (lane-local l), pack pairs, 8B stores
  const float inv = 1.f / l;
  unsigned short* orow = Xo + (size_t)(b * S + qrow) * Dm + h * 64;
#pragma unroll
  for (int rq = 0; rq < 4; ++rq) {
    uint2 pr;
    pr.x = cvtpk_bf16(ot0[4 * rq + 0] * inv, ot0[4 * rq + 1] * inv);
    pr.y = cvtpk_bf16(ot0[4 * rq + 2] * inv, ot0[4 * rq + 3] * inv);
    *(uint2*)(orow + 8 * rq + 4 * hi) = pr;
    uint2 pr1;
    pr1.x = cvtpk_bf16(ot1[4 * rq + 0] * inv, ot1[4 * rq + 1] * inv);
    pr1.y = cvtpk_bf16(ot1[4 * rq + 2] * inv, ot1[4 * rq + 3] * inv);
    *(uint2*)(orow + 32 + 8 * rq + 4 * hi) = pr1;
  }
}

// ---------------- launch ----------------
extern "C" void kernel_launch(void* const* d_in, const int* in_sizes, int n_in,
                              void* d_out, int out_size, void* d_ws, size_t ws_size,
                              hipStream_t stream) {
  const float* query = (const float*)d_in[0];
  const float* key   = (const float*)d_in[1];
  const float* value = (const float*)d_in[2];
  const float* Wq = (const float*)d_in[4];
  const float* bq = (const float*)d_in[5];
  const float* Wk = (const float*)d_in[6];
  const float* bk = (const float*)d_in[7];
  const float* Wv = (const float*)d_in[8];
  const float* bv = (const float*)d_in[9];
  const float* Wo = (const float*)d_in[10];
  const float* bo = (const float*)d_in[11];

  constexpr int B = 4, S = 2048, D = 1024;
  constexpr int M = B * S;
  const size_t MB = 1024u * 1024u;
  uint8_t* ws = (uint8_t*)d_ws;

  unsigned short* Xq  = (unsigned short*)(ws + 0);
  unsigned short* Xk  = (unsigned short*)(ws + 16 * MB);
  unsigned short* Xv  = (unsigned short*)(ws + 32 * MB);
  unsigned short* Wqb = (unsigned short*)(ws + 48 * MB);
  unsigned short* Wkb = (unsigned short*)(ws + 50 * MB);
  unsigned short* Wvb = (unsigned short*)(ws + 52 * MB);
  unsigned short* Wob = (unsigned short*)(ws + 54 * MB);
  unsigned short* Qp  = (unsigned short*)(ws + 56 * MB);
  unsigned short* Kp  = (unsigned short*)(ws + 72 * MB);
  unsigned short* Vp  = (unsigned short*)(ws + 0);        // reuse Xq
  unsigned short* Vt  = (unsigned short*)(ws + 32 * MB);  // reuse Xv
  unsigned short* Xat = (unsigned short*)(ws + 16 * MB);  // reuse Xk

  const int nAct4 = M * D / 4, nW4 = D * D / 4;
  cast_bf16<<<(nAct4 + 255) / 256, 256, 0, stream>>>(query, Xq, nAct4);
  cast_bf16<<<(nAct4 + 255) / 256, 256, 0, stream>>>(key,   Xk, nAct4);
  cast_bf16<<<(nAct4 + 255) / 256, 256, 0, stream>>>(value, Xv, nAct4);
  cast_bf16<<<(nW4 + 255) / 256, 256, 0, stream>>>(Wq, Wqb, nW4);
  cast_bf16<<<(nW4 + 255) / 256, 256, 0, stream>>>(Wk, Wkb, nW4);
  cast_bf16<<<(nW4 + 255) / 256, 256, 0, stream>>>(Wv, Wvb, nW4);
  cast_bf16<<<(nW4 + 255) / 256, 256, 0, stream>>>(Wo, Wob, nW4);

  dim3 gg(D / 128, M / 128);
  gemm_bt<false, true ><<<gg, 256, 0, stream>>>(Xq, Wqb, bq, Qp, nullptr, M, D, D);
  gemm_bt<false, false><<<gg, 256, 0, stream>>>(Xk, Wkb, bk, Kp, nullptr, M, D, D);
  gemm_bt<false, false><<<gg, 256, 0, stream>>>(Xv, Wvb, bv, Vp, nullptr, M, D, D);

  transpose_v<<<dim3(64, S / 64), 256, 0, stream>>>(Vp, Vt);

  attn_fwd32p<<<4096, 64, 0, stream>>>(Qp, Kp, Vt, Xat);

  gemm_bt<true, false><<<gg, 256, 0, stream>>>(Xat, Wob, bo, nullptr, (float*)d_out, M, D, D);
}

// Round 7
// 300.116 us; speedup vs baseline: 1.0077x; 1.0077x over previous
//
#include <hip/hip_runtime.h>
#include <cstdint>
#include <cstddef>

// MHA: out = softmax_causal((XqWq^T+bq)(XkWk^T+bk)^T / 8) (XvWv^T+bv) Wo^T + bo
// B=4 S=2048 D=1024 H=16 dk=64. bf16 MFMA, fp32 accum. Softmax in exp2 domain:
// Q projection pre-scaled by 0.125*log2(e).
// ws: [0,16M) Xq->Vp ; [16M,32M) Xk->Xattn ; [32M,48M) Xv->Vt ;
// [48M,56M) weights bf16 ; [56M,72M) Qp ; [72M,88M) Kp.
// NOTE (R6 errata): FETCH_SIZE is KB -> attn fetches ~25 MB (working set once);
// no L2 refetch problem exists. Bottleneck is exposed load latency + occupancy
// decay. Fix: 4-wave blocks sharing one head's K/V stream (L1 hits for 3/4
// waves), lockstep via per-tile s_barrier, uniform block work.

typedef __attribute__((ext_vector_type(8))) short bf16x8;
typedef __attribute__((ext_vector_type(4))) float f32x4;
typedef __attribute__((ext_vector_type(16))) float f32x16;

__device__ __forceinline__ unsigned short f2bf(float f) {
  union { float f; unsigned u; } x; x.f = f;
  unsigned r = x.u + 0x7FFFu + ((x.u >> 16) & 1u);   // RNE
  return (unsigned short)(r >> 16);
}

__device__ __forceinline__ unsigned cvtpk_bf16(float lo, float hi) {
  unsigned r;
  asm("v_cvt_pk_bf16_f32 %0, %1, %2" : "=v"(r) : "v"(lo), "v"(hi));
  return r;
}

__device__ __forceinline__ f32x16 mfma32(bf16x8 a, bf16x8 b, f32x16 c) {
  return __builtin_amdgcn_mfma_f32_32x32x16_bf16(a, b, c, 0, 0, 0);
}

__device__ __forceinline__ void gld16(unsigned short* lds, const unsigned short* g) {
  __builtin_amdgcn_global_load_lds(
      (const __attribute__((address_space(1))) unsigned int*)g,
      (__attribute__((address_space(3))) unsigned int*)lds, 16, 0, 0);
}

// ---------------- fp32 -> bf16 cast ----------------
__global__ __launch_bounds__(256) void cast_bf16(const float* __restrict__ src,
                                                 unsigned short* __restrict__ dst, int n4) {
  const int i = blockIdx.x * 256 + threadIdx.x;
  if (i >= n4) return;
  const float4 f = ((const float4*)src)[i];
  ushort4 o;
  o.x = f2bf(f.x); o.y = f2bf(f.y); o.z = f2bf(f.z); o.w = f2bf(f.w);
  ((ushort4*)dst)[i] = o;
}

// ---------------- GEMM: C[m,n] = sum_k A[m,k]*W[n,k] + bias[n] ----------------
template <bool F32OUT, bool SCALEQ>
__global__ __launch_bounds__(256)
void gemm_bt(const unsigned short* __restrict__ A,
             const unsigned short* __restrict__ Bw,
             const float* __restrict__ bias,
             unsigned short* __restrict__ Cb,
             float* __restrict__ Cf,
             int M, int N, int K) {
  __shared__ unsigned short As[128 * 32];
  __shared__ unsigned short Bs[128 * 32];
  const int tid = threadIdx.x;
  const int lane = tid & 63;
  const int w = tid >> 6;
  const int wm = (w >> 1) * 64;
  const int wn = (w & 1) * 64;
  const int m0 = blockIdx.y * 128;
  const int n0 = blockIdx.x * 128;
  const int l15 = lane & 15, l4 = lane >> 4;

  f32x4 acc[4][4] = {};

  const int c0 = tid, c1 = 256 + tid;
  const int r0 = c0 >> 2, kc0 = (c0 & 3) * 8;
  const int r1 = c1 >> 2, kc1 = (c1 & 3) * 8;

  for (int k0 = 0; k0 < K; k0 += 32) {
    __syncthreads();
    gld16(&As[c0 * 8], &A[(size_t)(m0 + r0) * K + k0 + kc0]);
    gld16(&As[c1 * 8], &A[(size_t)(m0 + r1) * K + k0 + kc1]);
    gld16(&Bs[c0 * 8], &Bw[(size_t)(n0 + r0) * K + k0 + kc0]);
    gld16(&Bs[c1 * 8], &Bw[(size_t)(n0 + r1) * K + k0 + kc1]);
    __syncthreads();

    bf16x8 af[4], bfr[4];
#pragma unroll
    for (int m = 0; m < 4; ++m)
      af[m] = *(const bf16x8*)&As[(wm + m * 16 + l15) * 32 + l4 * 8];
#pragma unroll
    for (int n = 0; n < 4; ++n)
      bfr[n] = *(const bf16x8*)&Bs[(wn + n * 16 + l15) * 32 + l4 * 8];
#pragma unroll
    for (int m = 0; m < 4; ++m)
#pragma unroll
      for (int n = 0; n < 4; ++n)
        acc[m][n] = __builtin_amdgcn_mfma_f32_16x16x32_bf16(af[m], bfr[n], acc[m][n], 0, 0, 0);
  }

  const int crow = l4 * 4;
#pragma unroll
  for (int m = 0; m < 4; ++m) {
#pragma unroll
    for (int n = 0; n < 4; ++n) {
      const int col = n0 + wn + n * 16 + l15;
      const float bv_ = bias[col];
#pragma unroll
      for (int j = 0; j < 4; ++j) {
        const int row = m0 + wm + m * 16 + crow + j;
        float v = acc[m][n][j] + bv_;
        if constexpr (SCALEQ) v *= 0.125f * 1.44269504f;  // 1/sqrt(dk) * log2(e)
        if constexpr (F32OUT) Cf[(size_t)row * N + col] = v;
        else                  Cb[(size_t)row * N + col] = f2bf(v);
      }
    }
  }
}

// ---------------- V transpose: [b,s,h*64+d] -> [(b*16+h)*64+d, s] ----------------
__global__ __launch_bounds__(256)
void transpose_v(const unsigned short* __restrict__ Vp, unsigned short* __restrict__ Vt) {
  constexpr int S = 2048, Dm = 1024;
  __shared__ __align__(16) unsigned short t[64][72];
  const int bh = blockIdx.x, b = bh >> 4, h = bh & 15;
  const int s0 = blockIdx.y * 64;
  const int tid = threadIdx.x;
#pragma unroll
  for (int r = 0; r < 2; ++r) {
    const int c = r * 256 + tid;
    const int sl = c >> 3, d8 = (c & 7) * 8;
    *(bf16x8*)&t[sl][d8] =
        *(const bf16x8*)&Vp[(size_t)(b * S + s0 + sl) * Dm + h * 64 + d8];
  }
  __syncthreads();
#pragma unroll
  for (int r = 0; r < 2; ++r) {
    const int c = r * 256 + tid;
    const int dl = c >> 3, s8 = (c & 7) * 8;
    bf16x8 ov;
#pragma unroll
    for (int jj = 0; jj < 8; ++jj) ov[jj] = t[s8 + jj][dl];
    *(bf16x8*)&Vt[(size_t)(bh * 64 + dl) * S + s0 + s8] = ov;
  }
}

// ---------------- flash attention, causal, cooperative 4-wave blocks ----------------
// Block = one head (bh) x 4 adjacent q-blocks {4g..4g+3}; wave w owns q-block 4g+w.
// All 4 waves read IDENTICAL K/V tile addresses -> leader misses, rest hit L1.
// Per-tile s_barrier keeps waves lockstep (scheduling only; no LDS, no exchange).
// Uniform trip count NT=4g+4; waves predicate compute on t < ntw.
// Swapped QK^T (col=q lane-local softmax), O^T via A=V^T. KVBLK=32, K ping-pong
// prefetch. exp2 domain. Blocks longest-first (g descending).
__global__ __launch_bounds__(256)
void attn_fwd32b(const unsigned short* __restrict__ Qp,   // [B*S,1024] bf16 (scaled)
                 const unsigned short* __restrict__ Kp,   // [B*S,1024] bf16
                 const unsigned short* __restrict__ Vt,   // [(b*16+h)*64+d, S] bf16
                 unsigned short* __restrict__ Xo) {       // [B*S,1024] bf16
  constexpr int S = 2048, Dm = 1024;
  const int bh = blockIdx.x & 63;
  const int g  = 15 - (int)(blockIdx.x >> 6);   // longest blocks first
  const int b = bh >> 4, h = bh & 15;
  const int w = threadIdx.x >> 6;
  const int lane = threadIdx.x & 63;
  const int l31 = lane & 31, hi = lane >> 5;
  const int qb = 4 * g + w;
  const int qrow = qb * 32 + l31;
  const int ntw = qb + 1;          // this wave's KV tiles; tile ntw-1 masked
  const int NT = 4 * g + 4;        // uniform block trip count (even)

  // Q B-frags: col=q=l31, k(d)=c*16+hi*8
  const unsigned short* qptr = Qp + (size_t)(b * S + qrow) * Dm + h * 64 + hi * 8;
  bf16x8 qf[4];
#pragma unroll
  for (int c = 0; c < 4; ++c) qf[c] = *(const bf16x8*)(qptr + c * 16);

  const unsigned short* kbase = Kp + (size_t)(b * S) * Dm + h * 64 + hi * 8;
  const unsigned short* vr0 = Vt + (size_t)(bh * 64 + l31) * S + hi * 8;
  const unsigned short* vr1 = vr0 + (size_t)32 * S;

  f32x16 ot0 = {}, ot1 = {};   // O^T: rows d (0-31 / 32-63), col q=l31
  float m = -1e30f, l = 0.f;

  auto loadK = [&](bf16x8 (&kr)[4], int t) {
    const unsigned short* krow = kbase + (size_t)(t * 32 + l31) * Dm;
#pragma unroll
    for (int c = 0; c < 4; ++c) kr[c] = *(const bf16x8*)(krow + c * 16);
  };

  auto body = [&](bf16x8 (&kr)[4], int t) {
    const int kv0 = t * 32;
    // V loads issued early; consumed after softmax
    const bf16x8 vf0a = *(const bf16x8*)(vr0 + kv0);
    const bf16x8 vf0b = *(const bf16x8*)(vr0 + kv0 + 16);
    const bf16x8 vf1a = *(const bf16x8*)(vr1 + kv0);
    const bf16x8 vf1b = *(const bf16x8*)(vr1 + kv0 + 16);
    // S^T = K · Q  (rows kv, col q)
    f32x16 ts = {};
#pragma unroll
    for (int c = 0; c < 4; ++c) ts = mfma32(kr[c], qf[c], ts);
    if (t == ntw - 1) {   // diagonal tile
#pragma unroll
      for (int r = 0; r < 16; ++r) {
        const int kvp = kv0 + (r & 3) + 8 * (r >> 2) + 4 * hi;
        if (kvp > qrow) ts[r] = -1e9f;
      }
    }
    // row max: lane-local + 1 cross-half shfl
    float pmax = ts[0];
#pragma unroll
    for (int r = 1; r < 16; ++r) pmax = fmaxf(pmax, ts[r]);
    pmax = fmaxf(pmax, __shfl_xor(pmax, 32));
    // deferred rescale (T13; log2 units)
    if (__any(pmax > m + 11.5f)) {
      const float mn = (pmax > m + 11.5f) ? pmax : m;
      const float fct = __builtin_amdgcn_exp2f(m - mn);
      m = mn; l *= fct;
#pragma unroll
      for (int r = 0; r < 16; ++r) { ot0[r] *= fct; ot1[r] *= fct; }
    }
    // p = 2^(s-m), row-sum
    float p[16], ls = 0.f;
#pragma unroll
    for (int r = 0; r < 16; ++r) {
      p[r] = __builtin_amdgcn_exp2f(ts[r] - m);
      ls += p[r];
    }
    ls += __shfl_xor(ls, 32);
    l += ls;
    // pack bf16 pairs + cross-half exchange -> P^T B-frags (k=kv)
    unsigned ua[8];
#pragma unroll
    for (int i = 0; i < 8; ++i) ua[i] = cvtpk_bf16(p[2 * i], p[2 * i + 1]);
    union FR { bf16x8 v; unsigned u[4]; } fr0, fr1;
    {
      unsigned sa = hi ? ua[0] : ua[2], sb = hi ? ua[1] : ua[3];
      unsigned xa = __shfl_xor(sa, 32), xb = __shfl_xor(sb, 32);
      fr0.u[0] = hi ? xa : ua[0]; fr0.u[1] = hi ? xb : ua[1];
      fr0.u[2] = hi ? ua[2] : xa; fr0.u[3] = hi ? ua[3] : xb;
      unsigned sc = hi ? ua[4] : ua[6], sd = hi ? ua[5] : ua[7];
      unsigned xc = __shfl_xor(sc, 32), xd = __shfl_xor(sd, 32);
      fr1.u[0] = hi ? xc : ua[4]; fr1.u[1] = hi ? xd : ua[5];
      fr1.u[2] = hi ? ua[6] : xc; fr1.u[3] = hi ? ua[7] : xd;
    }
    // O^T += V^T · P^T
    ot0 = mfma32(vf0a, fr0.v, ot0);
    ot0 = mfma32(vf0b, fr1.v, ot0);
    ot1 = mfma32(vf1a, fr0.v, ot1);
    ot1 = mfma32(vf1b, fr1.v, ot1);
  };

  // ping-pong K prefetch; identical loads across the 4 waves (L1-shared).
  // Loop bounds uniform across the block; compute predicated per wave.
  bf16x8 kA[4], kB[4];
  loadK(kA, 0);
  for (int t = 0; t < NT; t += 2) {
    loadK(kB, t + 1);
    if (t < ntw) body(kA, t);
    __builtin_amdgcn_s_barrier();
    const int t2 = (t + 2 < NT) ? (t + 2) : (NT - 1);  // clamped (redundant on last)
    loadK(kA, t2);
    if (t + 1 < ntw) body(kB, t + 1);
    __builtin_amdgcn_s_barrier();
  }

  // epilogue: normalize (lane-local l), pack pairs, 8B stores
  const float inv = 1.f / l;
  unsigned short* orow = Xo + (size_t)(b * S + qrow) * Dm + h * 64;
#pragma unroll
  for (int rq = 0; rq < 4; ++rq) {
    uint2 pr;
    pr.x = cvtpk_bf16(ot0[4 * rq + 0] * inv, ot0[4 * rq + 1] * inv);
    pr.y = cvtpk_bf16(ot0[4 * rq + 2] * inv, ot0[4 * rq + 3] * inv);
    *(uint2*)(orow + 8 * rq + 4 * hi) = pr;
    uint2 pr1;
    pr1.x = cvtpk_bf16(ot1[4 * rq + 0] * inv, ot1[4 * rq + 1] * inv);
    pr1.y = cvtpk_bf16(ot1[4 * rq + 2] * inv, ot1[4 * rq + 3] * inv);
    *(uint2*)(orow + 32 + 8 * rq + 4 * hi) = pr1;
  }
}

// ---------------- launch ----------------
extern "C" void kernel_launch(void* const* d_in, const int* in_sizes, int n_in,
                              void* d_out, int out_size, void* d_ws, size_t ws_size,
                              hipStream_t stream) {
  const float* query = (const float*)d_in[0];
  const float* key   = (const float*)d_in[1];
  const float* value = (const float*)d_in[2];
  const float* Wq = (const float*)d_in[4];
  const float* bq = (const float*)d_in[5];
  const float* Wk = (const float*)d_in[6];
  const float* bk = (const float*)d_in[7];
  const float* Wv = (const float*)d_in[8];
  const float* bv = (const float*)d_in[9];
  const float* Wo = (const float*)d_in[10];
  const float* bo = (const float*)d_in[11];

  constexpr int B = 4, S = 2048, D = 1024;
  constexpr int M = B * S;
  const size_t MB = 1024u * 1024u;
  uint8_t* ws = (uint8_t*)d_ws;

  unsigned short* Xq  = (unsigned short*)(ws + 0);
  unsigned short* Xk  = (unsigned short*)(ws + 16 * MB);
  unsigned short* Xv  = (unsigned short*)(ws + 32 * MB);
  unsigned short* Wqb = (unsigned short*)(ws + 48 * MB);
  unsigned short* Wkb = (unsigned short*)(ws + 50 * MB);
  unsigned short* Wvb = (unsigned short*)(ws + 52 * MB);
  unsigned short* Wob = (unsigned short*)(ws + 54 * MB);
  unsigned short* Qp  = (unsigned short*)(ws + 56 * MB);
  unsigned short* Kp  = (unsigned short*)(ws + 72 * MB);
  unsigned short* Vp  = (unsigned short*)(ws + 0);        // reuse Xq
  unsigned short* Vt  = (unsigned short*)(ws + 32 * MB);  // reuse Xv
  unsigned short* Xat = (unsigned short*)(ws + 16 * MB);  // reuse Xk

  const int nAct4 = M * D / 4, nW4 = D * D / 4;
  cast_bf16<<<(nAct4 + 255) / 256, 256, 0, stream>>>(query, Xq, nAct4);
  cast_bf16<<<(nAct4 + 255) / 256, 256, 0, stream>>>(key,   Xk, nAct4);
  cast_bf16<<<(nAct4 + 255) / 256, 256, 0, stream>>>(value, Xv, nAct4);
  cast_bf16<<<(nW4 + 255) / 256, 256, 0, stream>>>(Wq, Wqb, nW4);
  cast_bf16<<<(nW4 + 255) / 256, 256, 0, stream>>>(Wk, Wkb, nW4);
  cast_bf16<<<(nW4 + 255) / 256, 256, 0, stream>>>(Wv, Wvb, nW4);
  cast_bf16<<<(nW4 + 255) / 256, 256, 0, stream>>>(Wo, Wob, nW4);

  dim3 gg(D / 128, M / 128);
  gemm_bt<false, true ><<<gg, 256, 0, stream>>>(Xq, Wqb, bq, Qp, nullptr, M, D, D);
  gemm_bt<false, false><<<gg, 256, 0, stream>>>(Xk, Wkb, bk, Kp, nullptr, M, D, D);
  gemm_bt<false, false><<<gg, 256, 0, stream>>>(Xv, Wvb, bv, Vp, nullptr, M, D, D);

  transpose_v<<<dim3(64, S / 64), 256, 0, stream>>>(Vp, Vt);

  attn_fwd32b<<<1024, 256, 0, stream>>>(Qp, Kp, Vt, Xat);

  gemm_bt<true, false><<<gg, 256, 0, stream>>>(Xat, Wob, bo, nullptr, (float*)d_out, M, D, D);
}

// Round 11
// 288.997 us; speedup vs baseline: 1.0464x; 1.0385x over previous
//
#include <hip/hip_runtime.h>
#include <cstdint>
#include <cstddef>

// MHA: out = softmax_causal((XqWq^T+bq)(XkWk^T+bk)^T / 8) (XvWv^T+bv) Wo^T + bo
// B=4 S=2048 D=1024 H=16 dk=64. bf16 MFMA, fp32 accum. exp2-domain softmax
// (Q projection pre-scaled by 0.125*log2(e)).
// R10: re-anchor = EXACT R6 source (passed 300.1us) for gemm_bt/transpose_v/
// attn_fwd32b/layout. Only change: 7 cast launches fused into one cast_all.
// R7/R8/R9 attn-side edits all failed with ~1e9 absmax; R9 was proven
// semantically identical to R6 -> baseline reproducibility under test here.

typedef __attribute__((ext_vector_type(8))) short bf16x8;
typedef __attribute__((ext_vector_type(4))) float f32x4;
typedef __attribute__((ext_vector_type(16))) float f32x16;

__device__ __forceinline__ unsigned short f2bf(float f) {
  union { float f; unsigned u; } x; x.f = f;
  unsigned r = x.u + 0x7FFFu + ((x.u >> 16) & 1u);   // RNE
  return (unsigned short)(r >> 16);
}

__device__ __forceinline__ unsigned cvtpk_bf16(float lo, float hi) {
  unsigned r;
  asm("v_cvt_pk_bf16_f32 %0, %1, %2" : "=v"(r) : "v"(lo), "v"(hi));
  return r;
}

__device__ __forceinline__ f32x16 mfma32(bf16x8 a, bf16x8 b, f32x16 c) {
  return __builtin_amdgcn_mfma_f32_32x32x16_bf16(a, b, c, 0, 0, 0);
}

__device__ __forceinline__ void gld16(unsigned short* lds, const unsigned short* g) {
  __builtin_amdgcn_global_load_lds(
      (const __attribute__((address_space(1))) unsigned int*)g,
      (__attribute__((address_space(3))) unsigned int*)lds, 16, 0, 0);
}

// ---------------- fused fp32 -> bf16 cast (7 regions, 1 launch) ----------------
// Regions (float4 units): 3 activations of A4 each, then 4 weights of W4 each.
// A4 and W4 are multiples of 256 -> every block is region-uniform.
__global__ __launch_bounds__(256)
void cast_all(const float* __restrict__ q, const float* __restrict__ k,
              const float* __restrict__ v, const float* __restrict__ wq,
              const float* __restrict__ wk, const float* __restrict__ wv,
              const float* __restrict__ wo,
              unsigned short* __restrict__ xq, unsigned short* __restrict__ xk,
              unsigned short* __restrict__ xv, unsigned short* __restrict__ wqb,
              unsigned short* __restrict__ wkb, unsigned short* __restrict__ wvb,
              unsigned short* __restrict__ wob) {
  constexpr int A4 = 8192 * 1024 / 4;   // 2,097,152
  constexpr int W4 = 1024 * 1024 / 4;   //   262,144
  const int i = blockIdx.x * 256 + threadIdx.x;
  const float* src;
  unsigned short* dst;
  int off;
  if (i < 3 * A4) {
    const int r = i / A4;
    off = i - r * A4;
    src = (r == 0) ? q : (r == 1) ? k : v;
    dst = (r == 0) ? xq : (r == 1) ? xk : xv;
  } else {
    const int j = i - 3 * A4;
    const int r = j / W4;
    off = j - r * W4;
    src = (r == 0) ? wq : (r == 1) ? wk : (r == 2) ? wv : wo;
    dst = (r == 0) ? wqb : (r == 1) ? wkb : (r == 2) ? wvb : wob;
  }
  const float4 f = ((const float4*)src)[off];
  ushort4 o;
  o.x = f2bf(f.x); o.y = f2bf(f.y); o.z = f2bf(f.z); o.w = f2bf(f.w);
  ((ushort4*)dst)[off] = o;
}

// ---------------- GEMM: C[m,n] = sum_k A[m,k]*W[n,k] + bias[n] ----------------
template <bool F32OUT, bool SCALEQ>
__global__ __launch_bounds__(256)
void gemm_bt(const unsigned short* __restrict__ A,
             const unsigned short* __restrict__ Bw,
             const float* __restrict__ bias,
             unsigned short* __restrict__ Cb,
             float* __restrict__ Cf,
             int M, int N, int K) {
  __shared__ unsigned short As[128 * 32];
  __shared__ unsigned short Bs[128 * 32];
  const int tid = threadIdx.x;
  const int lane = tid & 63;
  const int w = tid >> 6;
  const int wm = (w >> 1) * 64;
  const int wn = (w & 1) * 64;
  const int m0 = blockIdx.y * 128;
  const int n0 = blockIdx.x * 128;
  const int l15 = lane & 15, l4 = lane >> 4;

  f32x4 acc[4][4] = {};

  const int c0 = tid, c1 = 256 + tid;
  const int r0 = c0 >> 2, kc0 = (c0 & 3) * 8;
  const int r1 = c1 >> 2, kc1 = (c1 & 3) * 8;

  for (int k0 = 0; k0 < K; k0 += 32) {
    __syncthreads();
    gld16(&As[c0 * 8], &A[(size_t)(m0 + r0) * K + k0 + kc0]);
    gld16(&As[c1 * 8], &A[(size_t)(m0 + r1) * K + k0 + kc1]);
    gld16(&Bs[c0 * 8], &Bw[(size_t)(n0 + r0) * K + k0 + kc0]);
    gld16(&Bs[c1 * 8], &Bw[(size_t)(n0 + r1) * K + k0 + kc1]);
    __syncthreads();

    bf16x8 af[4], bfr[4];
#pragma unroll
    for (int m = 0; m < 4; ++m)
      af[m] = *(const bf16x8*)&As[(wm + m * 16 + l15) * 32 + l4 * 8];
#pragma unroll
    for (int n = 0; n < 4; ++n)
      bfr[n] = *(const bf16x8*)&Bs[(wn + n * 16 + l15) * 32 + l4 * 8];
#pragma unroll
    for (int m = 0; m < 4; ++m)
#pragma unroll
      for (int n = 0; n < 4; ++n)
        acc[m][n] = __builtin_amdgcn_mfma_f32_16x16x32_bf16(af[m], bfr[n], acc[m][n], 0, 0, 0);
  }

  const int crow = l4 * 4;
#pragma unroll
  for (int m = 0; m < 4; ++m) {
#pragma unroll
    for (int n = 0; n < 4; ++n) {
      const int col = n0 + wn + n * 16 + l15;
      const float bv_ = bias[col];
#pragma unroll
      for (int j = 0; j < 4; ++j) {
        const int row = m0 + wm + m * 16 + crow + j;
        float v = acc[m][n][j] + bv_;
        if constexpr (SCALEQ) v *= 0.125f * 1.44269504f;  // 1/sqrt(dk) * log2(e)
        if constexpr (F32OUT) Cf[(size_t)row * N + col] = v;
        else                  Cb[(size_t)row * N + col] = f2bf(v);
      }
    }
  }
}

// ---------------- V transpose: [b,s,h*64+d] -> [(b*16+h)*64+d, s] ----------------
__global__ __launch_bounds__(256)
void transpose_v(const unsigned short* __restrict__ Vp, unsigned short* __restrict__ Vt) {
  constexpr int S = 2048, Dm = 1024;
  __shared__ __align__(16) unsigned short t[64][72];
  const int bh = blockIdx.x, b = bh >> 4, h = bh & 15;
  const int s0 = blockIdx.y * 64;
  const int tid = threadIdx.x;
#pragma unroll
  for (int r = 0; r < 2; ++r) {
    const int c = r * 256 + tid;
    const int sl = c >> 3, d8 = (c & 7) * 8;
    *(bf16x8*)&t[sl][d8] =
        *(const bf16x8*)&Vp[(size_t)(b * S + s0 + sl) * Dm + h * 64 + d8];
  }
  __syncthreads();
#pragma unroll
  for (int r = 0; r < 2; ++r) {
    const int c = r * 256 + tid;
    const int dl = c >> 3, s8 = (c & 7) * 8;
    bf16x8 ov;
#pragma unroll
    for (int jj = 0; jj < 8; ++jj) ov[jj] = t[s8 + jj][dl];
    *(bf16x8*)&Vt[(size_t)(bh * 64 + dl) * S + s0 + s8] = ov;
  }
}

// ---------------- flash attention, causal, cooperative 4-wave blocks ----------------
// Block = one head (bh) x 4 adjacent q-blocks {4g..4g+3}; wave w owns q-block 4g+w.
// All 4 waves read IDENTICAL K/V tile addresses -> leader misses, rest hit L1.
// Per-tile s_barrier keeps waves lockstep (scheduling only; no LDS, no exchange).
// Uniform trip count NT=4g+4; waves predicate compute on t < ntw.
// Swapped QK^T (col=q lane-local softmax), O^T via A=V^T. KVBLK=32, K ping-pong
// prefetch. exp2 domain. Blocks longest-first (g descending).
__global__ __launch_bounds__(256)
void attn_fwd32b(const unsigned short* __restrict__ Qp,   // [B*S,1024] bf16 (scaled)
                 const unsigned short* __restrict__ Kp,   // [B*S,1024] bf16
                 const unsigned short* __restrict__ Vt,   // [(b*16+h)*64+d, S] bf16
                 unsigned short* __restrict__ Xo) {       // [B*S,1024] bf16
  constexpr int S = 2048, Dm = 1024;
  const int bh = blockIdx.x & 63;
  const int g  = 15 - (int)(blockIdx.x >> 6);   // longest blocks first
  const int b = bh >> 4, h = bh & 15;
  const int w = threadIdx.x >> 6;
  const int lane = threadIdx.x & 63;
  const int l31 = lane & 31, hi = lane >> 5;
  const int qb = 4 * g + w;
  const int qrow = qb * 32 + l31;
  const int ntw = qb + 1;          // this wave's KV tiles; tile ntw-1 masked
  const int NT = 4 * g + 4;        // uniform block trip count (even)

  // Q B-frags: col=q=l31, k(d)=c*16+hi*8
  const unsigned short* qptr = Qp + (size_t)(b * S + qrow) * Dm + h * 64 + hi * 8;
  bf16x8 qf[4];
#pragma unroll
  for (int c = 0; c < 4; ++c) qf[c] = *(const bf16x8*)(qptr + c * 16);

  const unsigned short* kbase = Kp + (size_t)(b * S) * Dm + h * 64 + hi * 8;
  const unsigned short* vr0 = Vt + (size_t)(bh * 64 + l31) * S + hi * 8;
  const unsigned short* vr1 = vr0 + (size_t)32 * S;

  f32x16 ot0 = {}, ot1 = {};   // O^T: rows d (0-31 / 32-63), col q=l31
  float m = -1e30f, l = 0.f;

  auto loadK = [&](bf16x8 (&kr)[4], int t) {
    const unsigned short* krow = kbase + (size_t)(t * 32 + l31) * Dm;
#pragma unroll
    for (int c = 0; c < 4; ++c) kr[c] = *(const bf16x8*)(krow + c * 16);
  };

  auto body = [&](bf16x8 (&kr)[4], int t) {
    const int kv0 = t * 32;
    // V loads issued early; consumed after softmax
    const bf16x8 vf0a = *(const bf16x8*)(vr0 + kv0);
    const bf16x8 vf0b = *(const bf16x8*)(vr0 + kv0 + 16);
    const bf16x8 vf1a = *(const bf16x8*)(vr1 + kv0);
    const bf16x8 vf1b = *(const bf16x8*)(vr1 + kv0 + 16);
    // S^T = K · Q  (rows kv, col q)
    f32x16 ts = {};
#pragma unroll
    for (int c = 0; c < 4; ++c) ts = mfma32(kr[c], qf[c], ts);
    if (t == ntw - 1) {   // diagonal tile
#pragma unroll
      for (int r = 0; r < 16; ++r) {
        const int kvp = kv0 + (r & 3) + 8 * (r >> 2) + 4 * hi;
        if (kvp > qrow) ts[r] = -1e9f;
      }
    }
    // row max: lane-local + 1 cross-half shfl
    float pmax = ts[0];
#pragma unroll
    for (int r = 1; r < 16; ++r) pmax = fmaxf(pmax, ts[r]);
    pmax = fmaxf(pmax, __shfl_xor(pmax, 32));
    // deferred rescale (T13; log2 units)
    if (__any(pmax > m + 11.5f)) {
      const float mn = (pmax > m + 11.5f) ? pmax : m;
      const float fct = __builtin_amdgcn_exp2f(m - mn);
      m = mn; l *= fct;
#pragma unroll
      for (int r = 0; r < 16; ++r) { ot0[r] *= fct; ot1[r] *= fct; }
    }
    // p = 2^(s-m), row-sum
    float p[16], ls = 0.f;
#pragma unroll
    for (int r = 0; r < 16; ++r) {
      p[r] = __builtin_amdgcn_exp2f(ts[r] - m);
      ls += p[r];
    }
    ls += __shfl_xor(ls, 32);
    l += ls;
    // pack bf16 pairs + cross-half exchange -> P^T B-frags (k=kv)
    unsigned ua[8];
#pragma unroll
    for (int i = 0; i < 8; ++i) ua[i] = cvtpk_bf16(p[2 * i], p[2 * i + 1]);
    union FR { bf16x8 v; unsigned u[4]; } fr0, fr1;
    {
      unsigned sa = hi ? ua[0] : ua[2], sb = hi ? ua[1] : ua[3];
      unsigned xa = __shfl_xor(sa, 32), xb = __shfl_xor(sb, 32);
      fr0.u[0] = hi ? xa : ua[0]; fr0.u[1] = hi ? xb : ua[1];
      fr0.u[2] = hi ? ua[2] : xa; fr0.u[3] = hi ? ua[3] : xb;
      unsigned sc = hi ? ua[4] : ua[6], sd = hi ? ua[5] : ua[7];
      unsigned xc = __shfl_xor(sc, 32), xd = __shfl_xor(sd, 32);
      fr1.u[0] = hi ? xc : ua[4]; fr1.u[1] = hi ? xd : ua[5];
      fr1.u[2] = hi ? ua[6] : xc; fr1.u[3] = hi ? ua[7] : xd;
    }
    // O^T += V^T · P^T
    ot0 = mfma32(vf0a, fr0.v, ot0);
    ot0 = mfma32(vf0b, fr1.v, ot0);
    ot1 = mfma32(vf1a, fr0.v, ot1);
    ot1 = mfma32(vf1b, fr1.v, ot1);
  };

  // ping-pong K prefetch; identical loads across the 4 waves (L1-shared).
  // Loop bounds uniform across the block; compute predicated per wave.
  bf16x8 kA[4], kB[4];
  loadK(kA, 0);
  for (int t = 0; t < NT; t += 2) {
    loadK(kB, t + 1);
    if (t < ntw) body(kA, t);
    __builtin_amdgcn_s_barrier();
    const int t2 = (t + 2 < NT) ? (t + 2) : (NT - 1);  // clamped (redundant on last)
    loadK(kA, t2);
    if (t + 1 < ntw) body(kB, t + 1);
    __builtin_amdgcn_s_barrier();
  }

  // epilogue: normalize (lane-local l), pack pairs, 8B stores
  const float inv = 1.f / l;
  unsigned short* orow = Xo + (size_t)(b * S + qrow) * Dm + h * 64;
#pragma unroll
  for (int rq = 0; rq < 4; ++rq) {
    uint2 pr;
    pr.x = cvtpk_bf16(ot0[4 * rq + 0] * inv, ot0[4 * rq + 1] * inv);
    pr.y = cvtpk_bf16(ot0[4 * rq + 2] * inv, ot0[4 * rq + 3] * inv);
    *(uint2*)(orow + 8 * rq + 4 * hi) = pr;
    uint2 pr1;
    pr1.x = cvtpk_bf16(ot1[4 * rq + 0] * inv, ot1[4 * rq + 1] * inv);
    pr1.y = cvtpk_bf16(ot1[4 * rq + 2] * inv, ot1[4 * rq + 3] * inv);
    *(uint2*)(orow + 32 + 8 * rq + 4 * hi) = pr1;
  }
}

// ---------------- launch ----------------
extern "C" void kernel_launch(void* const* d_in, const int* in_sizes, int n_in,
                              void* d_out, int out_size, void* d_ws, size_t ws_size,
                              hipStream_t stream) {
  const float* query = (const float*)d_in[0];
  const float* key   = (const float*)d_in[1];
  const float* value = (const float*)d_in[2];
  const float* Wq = (const float*)d_in[4];
  const float* bq = (const float*)d_in[5];
  const float* Wk = (const float*)d_in[6];
  const float* bk = (const float*)d_in[7];
  const float* Wv = (const float*)d_in[8];
  const float* bv = (const float*)d_in[9];
  const float* Wo = (const float*)d_in[10];
  const float* bo = (const float*)d_in[11];

  constexpr int B = 4, S = 2048, D = 1024;
  constexpr int M = B * S;
  const size_t MB = 1024u * 1024u;
  uint8_t* ws = (uint8_t*)d_ws;

  unsigned short* Xq  = (unsigned short*)(ws + 0);
  unsigned short* Xk  = (unsigned short*)(ws + 16 * MB);
  unsigned short* Xv  = (unsigned short*)(ws + 32 * MB);
  unsigned short* Wqb = (unsigned short*)(ws + 48 * MB);
  unsigned short* Wkb = (unsigned short*)(ws + 50 * MB);
  unsigned short* Wvb = (unsigned short*)(ws + 52 * MB);
  unsigned short* Wob = (unsigned short*)(ws + 54 * MB);
  unsigned short* Qp  = (unsigned short*)(ws + 56 * MB);
  unsigned short* Kp  = (unsigned short*)(ws + 72 * MB);
  unsigned short* Vp  = (unsigned short*)(ws + 0);        // reuse Xq
  unsigned short* Vt  = (unsigned short*)(ws + 32 * MB);  // reuse Xv
  unsigned short* Xat = (unsigned short*)(ws + 16 * MB);  // reuse Xk

  // fused cast: 3*A4 + 4*W4 float4 units, exact multiple of 256
  constexpr int A4 = M * D / 4, W4 = D * D / 4;
  constexpr int NCAST = 3 * A4 + 4 * W4;
  cast_all<<<NCAST / 256, 256, 0, stream>>>(query, key, value, Wq, Wk, Wv, Wo,
                                            Xq, Xk, Xv, Wqb, Wkb, Wvb, Wob);

  dim3 gg(D / 128, M / 128);
  gemm_bt<false, true ><<<gg, 256, 0, stream>>>(Xq, Wqb, bq, Qp, nullptr, M, D, D);
  gemm_bt<false, false><<<gg, 256, 0, stream>>>(Xk, Wkb, bk, Kp, nullptr, M, D, D);
  gemm_bt<false, false><<<gg, 256, 0, stream>>>(Xv, Wvb, bv, Vp, nullptr, M, D, D);

  transpose_v<<<dim3(64, S / 64), 256, 0, stream>>>(Vp, Vt);

  attn_fwd32b<<<1024, 256, 0, stream>>>(Qp, Kp, Vt, Xat);

  gemm_bt<true, false><<<gg, 256, 0, stream>>>(Xat, Wob, bo, nullptr, (float*)d_out, M, D, D);
}

// Round 12
// 278.916 us; speedup vs baseline: 1.0843x; 1.0361x over previous
//
#include <hip/hip_runtime.h>
#include <cstdint>
#include <cstddef>

// MHA: out = softmax_causal((XqWq^T+bq)(XkWk^T+bk)^T / 8) (XvWv^T+bv) Wo^T + bo
// B=4 S=2048 D=1024 H=16 dk=64. bf16 MFMA, fp32 accum. exp2-domain softmax
// (Q projection pre-scaled by 0.125*log2(e)).
// R11: attn/cast/transpose FROZEN (= R10, passed 289us). Only change: gemm_bt
// grid flattened to 512 blocks with XCD-chunked decode (xcd=bid&7 owns 8
// M-panels, walks N fastest) so the 8 blocks sharing an A-panel run on ONE
// XCD's L2 instead of round-robining across all 8 (A was re-fetched 8x).

typedef __attribute__((ext_vector_type(8))) short bf16x8;
typedef __attribute__((ext_vector_type(4))) float f32x4;
typedef __attribute__((ext_vector_type(16))) float f32x16;

__device__ __forceinline__ unsigned short f2bf(float f) {
  union { float f; unsigned u; } x; x.f = f;
  unsigned r = x.u + 0x7FFFu + ((x.u >> 16) & 1u);   // RNE
  return (unsigned short)(r >> 16);
}

__device__ __forceinline__ unsigned cvtpk_bf16(float lo, float hi) {
  unsigned r;
  asm("v_cvt_pk_bf16_f32 %0, %1, %2" : "=v"(r) : "v"(lo), "v"(hi));
  return r;
}

__device__ __forceinline__ f32x16 mfma32(bf16x8 a, bf16x8 b, f32x16 c) {
  return __builtin_amdgcn_mfma_f32_32x32x16_bf16(a, b, c, 0, 0, 0);
}

__device__ __forceinline__ void gld16(unsigned short* lds, const unsigned short* g) {
  __builtin_amdgcn_global_load_lds(
      (const __attribute__((address_space(1))) unsigned int*)g,
      (__attribute__((address_space(3))) unsigned int*)lds, 16, 0, 0);
}

// ---------------- fused fp32 -> bf16 cast (7 regions, 1 launch) ----------------
__global__ __launch_bounds__(256)
void cast_all(const float* __restrict__ q, const float* __restrict__ k,
              const float* __restrict__ v, const float* __restrict__ wq,
              const float* __restrict__ wk, const float* __restrict__ wv,
              const float* __restrict__ wo,
              unsigned short* __restrict__ xq, unsigned short* __restrict__ xk,
              unsigned short* __restrict__ xv, unsigned short* __restrict__ wqb,
              unsigned short* __restrict__ wkb, unsigned short* __restrict__ wvb,
              unsigned short* __restrict__ wob) {
  constexpr int A4 = 8192 * 1024 / 4;   // 2,097,152
  constexpr int W4 = 1024 * 1024 / 4;   //   262,144
  const int i = blockIdx.x * 256 + threadIdx.x;
  const float* src;
  unsigned short* dst;
  int off;
  if (i < 3 * A4) {
    const int r = i / A4;
    off = i - r * A4;
    src = (r == 0) ? q : (r == 1) ? k : v;
    dst = (r == 0) ? xq : (r == 1) ? xk : xv;
  } else {
    const int j = i - 3 * A4;
    const int r = j / W4;
    off = j - r * W4;
    src = (r == 0) ? wq : (r == 1) ? wk : (r == 2) ? wv : wo;
    dst = (r == 0) ? wqb : (r == 1) ? wkb : (r == 2) ? wvb : wob;
  }
  const float4 f = ((const float4*)src)[off];
  ushort4 o;
  o.x = f2bf(f.x); o.y = f2bf(f.y); o.z = f2bf(f.z); o.w = f2bf(f.w);
  ((ushort4*)dst)[off] = o;
}

// ---------------- GEMM: C[m,n] = sum_k A[m,k]*W[n,k] + bias[n] ----------------
// Grid: flat 512 blocks. XCD-chunked decode (M=8192 -> 64 M-panels, N=1024 ->
// 8 N-tiles): xcd=bid&7 owns M-panels [8*xcd, 8*xcd+8), N walked fastest so
// consecutive same-XCD blocks reuse the A-panel from that XCD's L2.
template <bool F32OUT, bool SCALEQ>
__global__ __launch_bounds__(256)
void gemm_bt(const unsigned short* __restrict__ A,
             const unsigned short* __restrict__ Bw,
             const float* __restrict__ bias,
             unsigned short* __restrict__ Cb,
             float* __restrict__ Cf,
             int M, int N, int K) {
  __shared__ unsigned short As[128 * 32];
  __shared__ unsigned short Bs[128 * 32];
  const int tid = threadIdx.x;
  const int lane = tid & 63;
  const int w = tid >> 6;
  const int wm = (w >> 1) * 64;
  const int wn = (w & 1) * 64;
  const int bid = blockIdx.x;
  const int xcd = bid & 7, jj = bid >> 3;
  const int m0 = (xcd * 8 + (jj >> 3)) * 128;
  const int n0 = (jj & 7) * 128;
  const int l15 = lane & 15, l4 = lane >> 4;

  f32x4 acc[4][4] = {};

  const int c0 = tid, c1 = 256 + tid;
  const int r0 = c0 >> 2, kc0 = (c0 & 3) * 8;
  const int r1 = c1 >> 2, kc1 = (c1 & 3) * 8;

  for (int k0 = 0; k0 < K; k0 += 32) {
    __syncthreads();
    gld16(&As[c0 * 8], &A[(size_t)(m0 + r0) * K + k0 + kc0]);
    gld16(&As[c1 * 8], &A[(size_t)(m0 + r1) * K + k0 + kc1]);
    gld16(&Bs[c0 * 8], &Bw[(size_t)(n0 + r0) * K + k0 + kc0]);
    gld16(&Bs[c1 * 8], &Bw[(size_t)(n0 + r1) * K + k0 + kc1]);
    __syncthreads();

    bf16x8 af[4], bfr[4];
#pragma unroll
    for (int m = 0; m < 4; ++m)
      af[m] = *(const bf16x8*)&As[(wm + m * 16 + l15) * 32 + l4 * 8];
#pragma unroll
    for (int n = 0; n < 4; ++n)
      bfr[n] = *(const bf16x8*)&Bs[(wn + n * 16 + l15) * 32 + l4 * 8];
#pragma unroll
    for (int m = 0; m < 4; ++m)
#pragma unroll
      for (int n = 0; n < 4; ++n)
        acc[m][n] = __builtin_amdgcn_mfma_f32_16x16x32_bf16(af[m], bfr[n], acc[m][n], 0, 0, 0);
  }

  const int crow = l4 * 4;
#pragma unroll
  for (int m = 0; m < 4; ++m) {
#pragma unroll
    for (int n = 0; n < 4; ++n) {
      const int col = n0 + wn + n * 16 + l15;
      const float bv_ = bias[col];
#pragma unroll
      for (int j = 0; j < 4; ++j) {
        const int row = m0 + wm + m * 16 + crow + j;
        float v = acc[m][n][j] + bv_;
        if constexpr (SCALEQ) v *= 0.125f * 1.44269504f;  // 1/sqrt(dk) * log2(e)
        if constexpr (F32OUT) Cf[(size_t)row * N + col] = v;
        else                  Cb[(size_t)row * N + col] = f2bf(v);
      }
    }
  }
}

// ---------------- V transpose: [b,s,h*64+d] -> [(b*16+h)*64+d, s] ----------------
__global__ __launch_bounds__(256)
void transpose_v(const unsigned short* __restrict__ Vp, unsigned short* __restrict__ Vt) {
  constexpr int S = 2048, Dm = 1024;
  __shared__ __align__(16) unsigned short t[64][72];
  const int bh = blockIdx.x, b = bh >> 4, h = bh & 15;
  const int s0 = blockIdx.y * 64;
  const int tid = threadIdx.x;
#pragma unroll
  for (int r = 0; r < 2; ++r) {
    const int c = r * 256 + tid;
    const int sl = c >> 3, d8 = (c & 7) * 8;
    *(bf16x8*)&t[sl][d8] =
        *(const bf16x8*)&Vp[(size_t)(b * S + s0 + sl) * Dm + h * 64 + d8];
  }
  __syncthreads();
#pragma unroll
  for (int r = 0; r < 2; ++r) {
    const int c = r * 256 + tid;
    const int dl = c >> 3, s8 = (c & 7) * 8;
    bf16x8 ov;
#pragma unroll
    for (int jj = 0; jj < 8; ++jj) ov[jj] = t[s8 + jj][dl];
    *(bf16x8*)&Vt[(size_t)(bh * 64 + dl) * S + s0 + s8] = ov;
  }
}

// ---------------- flash attention, causal, cooperative 4-wave blocks ----------------
// FROZEN: byte-identical to R6/R10 (passed twice).
__global__ __launch_bounds__(256)
void attn_fwd32b(const unsigned short* __restrict__ Qp,   // [B*S,1024] bf16 (scaled)
                 const unsigned short* __restrict__ Kp,   // [B*S,1024] bf16
                 const unsigned short* __restrict__ Vt,   // [(b*16+h)*64+d, S] bf16
                 unsigned short* __restrict__ Xo) {       // [B*S,1024] bf16
  constexpr int S = 2048, Dm = 1024;
  const int bh = blockIdx.x & 63;
  const int g  = 15 - (int)(blockIdx.x >> 6);   // longest blocks first
  const int b = bh >> 4, h = bh & 15;
  const int w = threadIdx.x >> 6;
  const int lane = threadIdx.x & 63;
  const int l31 = lane & 31, hi = lane >> 5;
  const int qb = 4 * g + w;
  const int qrow = qb * 32 + l31;
  const int ntw = qb + 1;          // this wave's KV tiles; tile ntw-1 masked
  const int NT = 4 * g + 4;        // uniform block trip count (even)

  // Q B-frags: col=q=l31, k(d)=c*16+hi*8
  const unsigned short* qptr = Qp + (size_t)(b * S + qrow) * Dm + h * 64 + hi * 8;
  bf16x8 qf[4];
#pragma unroll
  for (int c = 0; c < 4; ++c) qf[c] = *(const bf16x8*)(qptr + c * 16);

  const unsigned short* kbase = Kp + (size_t)(b * S) * Dm + h * 64 + hi * 8;
  const unsigned short* vr0 = Vt + (size_t)(bh * 64 + l31) * S + hi * 8;
  const unsigned short* vr1 = vr0 + (size_t)32 * S;

  f32x16 ot0 = {}, ot1 = {};   // O^T: rows d (0-31 / 32-63), col q=l31
  float m = -1e30f, l = 0.f;

  auto loadK = [&](bf16x8 (&kr)[4], int t) {
    const unsigned short* krow = kbase + (size_t)(t * 32 + l31) * Dm;
#pragma unroll
    for (int c = 0; c < 4; ++c) kr[c] = *(const bf16x8*)(krow + c * 16);
  };

  auto body = [&](bf16x8 (&kr)[4], int t) {
    const int kv0 = t * 32;
    // V loads issued early; consumed after softmax
    const bf16x8 vf0a = *(const bf16x8*)(vr0 + kv0);
    const bf16x8 vf0b = *(const bf16x8*)(vr0 + kv0 + 16);
    const bf16x8 vf1a = *(const bf16x8*)(vr1 + kv0);
    const bf16x8 vf1b = *(const bf16x8*)(vr1 + kv0 + 16);
    // S^T = K · Q  (rows kv, col q)
    f32x16 ts = {};
#pragma unroll
    for (int c = 0; c < 4; ++c) ts = mfma32(kr[c], qf[c], ts);
    if (t == ntw - 1) {   // diagonal tile
#pragma unroll
      for (int r = 0; r < 16; ++r) {
        const int kvp = kv0 + (r & 3) + 8 * (r >> 2) + 4 * hi;
        if (kvp > qrow) ts[r] = -1e9f;
      }
    }
    // row max: lane-local + 1 cross-half shfl
    float pmax = ts[0];
#pragma unroll
    for (int r = 1; r < 16; ++r) pmax = fmaxf(pmax, ts[r]);
    pmax = fmaxf(pmax, __shfl_xor(pmax, 32));
    // deferred rescale (T13; log2 units)
    if (__any(pmax > m + 11.5f)) {
      const float mn = (pmax > m + 11.5f) ? pmax : m;
      const float fct = __builtin_amdgcn_exp2f(m - mn);
      m = mn; l *= fct;
#pragma unroll
      for (int r = 0; r < 16; ++r) { ot0[r] *= fct; ot1[r] *= fct; }
    }
    // p = 2^(s-m), row-sum
    float p[16], ls = 0.f;
#pragma unroll
    for (int r = 0; r < 16; ++r) {
      p[r] = __builtin_amdgcn_exp2f(ts[r] - m);
      ls += p[r];
    }
    ls += __shfl_xor(ls, 32);
    l += ls;
    // pack bf16 pairs + cross-half exchange -> P^T B-frags (k=kv)
    unsigned ua[8];
#pragma unroll
    for (int i = 0; i < 8; ++i) ua[i] = cvtpk_bf16(p[2 * i], p[2 * i + 1]);
    union FR { bf16x8 v; unsigned u[4]; } fr0, fr1;
    {
      unsigned sa = hi ? ua[0] : ua[2], sb = hi ? ua[1] : ua[3];
      unsigned xa = __shfl_xor(sa, 32), xb = __shfl_xor(sb, 32);
      fr0.u[0] = hi ? xa : ua[0]; fr0.u[1] = hi ? xb : ua[1];
      fr0.u[2] = hi ? ua[2] : xa; fr0.u[3] = hi ? ua[3] : xb;
      unsigned sc = hi ? ua[4] : ua[6], sd = hi ? ua[5] : ua[7];
      unsigned xc = __shfl_xor(sc, 32), xd = __shfl_xor(sd, 32);
      fr1.u[0] = hi ? xc : ua[4]; fr1.u[1] = hi ? xd : ua[5];
      fr1.u[2] = hi ? ua[6] : xc; fr1.u[3] = hi ? ua[7] : xd;
    }
    // O^T += V^T · P^T
    ot0 = mfma32(vf0a, fr0.v, ot0);
    ot0 = mfma32(vf0b, fr1.v, ot0);
    ot1 = mfma32(vf1a, fr0.v, ot1);
    ot1 = mfma32(vf1b, fr1.v, ot1);
  };

  // ping-pong K prefetch; identical loads across the 4 waves (L1-shared).
  bf16x8 kA[4], kB[4];
  loadK(kA, 0);
  for (int t = 0; t < NT; t += 2) {
    loadK(kB, t + 1);
    if (t < ntw) body(kA, t);
    __builtin_amdgcn_s_barrier();
    const int t2 = (t + 2 < NT) ? (t + 2) : (NT - 1);  // clamped (redundant on last)
    loadK(kA, t2);
    if (t + 1 < ntw) body(kB, t + 1);
    __builtin_amdgcn_s_barrier();
  }

  // epilogue: normalize (lane-local l), pack pairs, 8B stores
  const float inv = 1.f / l;
  unsigned short* orow = Xo + (size_t)(b * S + qrow) * Dm + h * 64;
#pragma unroll
  for (int rq = 0; rq < 4; ++rq) {
    uint2 pr;
    pr.x = cvtpk_bf16(ot0[4 * rq + 0] * inv, ot0[4 * rq + 1] * inv);
    pr.y = cvtpk_bf16(ot0[4 * rq + 2] * inv, ot0[4 * rq + 3] * inv);
    *(uint2*)(orow + 8 * rq + 4 * hi) = pr;
    uint2 pr1;
    pr1.x = cvtpk_bf16(ot1[4 * rq + 0] * inv, ot1[4 * rq + 1] * inv);
    pr1.y = cvtpk_bf16(ot1[4 * rq + 2] * inv, ot1[4 * rq + 3] * inv);
    *(uint2*)(orow + 32 + 8 * rq + 4 * hi) = pr1;
  }
}

// ---------------- launch ----------------
extern "C" void kernel_launch(void* const* d_in, const int* in_sizes, int n_in,
                              void* d_out, int out_size, void* d_ws, size_t ws_size,
                              hipStream_t stream) {
  const float* query = (const float*)d_in[0];
  const float* key   = (const float*)d_in[1];
  const float* value = (const float*)d_in[2];
  const float* Wq = (const float*)d_in[4];
  const float* bq = (const float*)d_in[5];
  const float* Wk = (const float*)d_in[6];
  const float* bk = (const float*)d_in[7];
  const float* Wv = (const float*)d_in[8];
  const float* bv = (const float*)d_in[9];
  const float* Wo = (const float*)d_in[10];
  const float* bo = (const float*)d_in[11];

  constexpr int B = 4, S = 2048, D = 1024;
  constexpr int M = B * S;
  const size_t MB = 1024u * 1024u;
  uint8_t* ws = (uint8_t*)d_ws;

  unsigned short* Xq  = (unsigned short*)(ws + 0);
  unsigned short* Xk  = (unsigned short*)(ws + 16 * MB);
  unsigned short* Xv  = (unsigned short*)(ws + 32 * MB);
  unsigned short* Wqb = (unsigned short*)(ws + 48 * MB);
  unsigned short* Wkb = (unsigned short*)(ws + 50 * MB);
  unsigned short* Wvb = (unsigned short*)(ws + 52 * MB);
  unsigned short* Wob = (unsigned short*)(ws + 54 * MB);
  unsigned short* Qp  = (unsigned short*)(ws + 56 * MB);
  unsigned short* Kp  = (unsigned short*)(ws + 72 * MB);
  unsigned short* Vp  = (unsigned short*)(ws + 0);        // reuse Xq
  unsigned short* Vt  = (unsigned short*)(ws + 32 * MB);  // reuse Xv
  unsigned short* Xat = (unsigned short*)(ws + 16 * MB);  // reuse Xk

  // fused cast: 3*A4 + 4*W4 float4 units, exact multiple of 256
  constexpr int A4 = M * D / 4, W4 = D * D / 4;
  constexpr int NCAST = 3 * A4 + 4 * W4;
  cast_all<<<NCAST / 256, 256, 0, stream>>>(query, key, value, Wq, Wk, Wv, Wo,
                                            Xq, Xk, Xv, Wqb, Wkb, Wvb, Wob);

  // projections: flat 512-block grid, XCD-chunked decode inside the kernel
  gemm_bt<false, true ><<<512, 256, 0, stream>>>(Xq, Wqb, bq, Qp, nullptr, M, D, D);
  gemm_bt<false, false><<<512, 256, 0, stream>>>(Xk, Wkb, bk, Kp, nullptr, M, D, D);
  gemm_bt<false, false><<<512, 256, 0, stream>>>(Xv, Wvb, bv, Vp, nullptr, M, D, D);

  transpose_v<<<dim3(64, S / 64), 256, 0, stream>>>(Vp, Vt);

  attn_fwd32b<<<1024, 256, 0, stream>>>(Qp, Kp, Vt, Xat);

  gemm_bt<true, false><<<512, 256, 0, stream>>>(Xat, Wob, bo, nullptr, (float*)d_out, M, D, D);
}

// Round 13
// 272.954 us; speedup vs baseline: 1.1079x; 1.0218x over previous
//
#include <hip/hip_runtime.h>
#include <cstdint>
#include <cstddef>

// MHA: out = softmax_causal((XqWq^T+bq)(XkWk^T+bk)^T / 8) (XvWv^T+bv) Wo^T + bo
// B=4 S=2048 D=1024 H=16 dk=64. bf16 MFMA, fp32 accum. exp2-domain softmax
// (Q projection pre-scaled by 0.125*log2(e)).
// R12: activation cast fused INTO the projection GEMMs (CASTA=true: A staged
// fp32->reg->cvt_pk->ds_write, identical LDS layout; B stays gld16 from
// pre-cast weights). Deletes cast_all's ~144MB of activation traffic.
// attn/transpose frozen (= R6/R10/R11, passed 3x). Wo-GEMM = CASTA=false,
// byte-identical staging to R11.

typedef __attribute__((ext_vector_type(8))) short bf16x8;
typedef __attribute__((ext_vector_type(4))) float f32x4;
typedef __attribute__((ext_vector_type(16))) float f32x16;

__device__ __forceinline__ unsigned short f2bf(float f) {
  union { float f; unsigned u; } x; x.f = f;
  unsigned r = x.u + 0x7FFFu + ((x.u >> 16) & 1u);   // RNE
  return (unsigned short)(r >> 16);
}

__device__ __forceinline__ unsigned cvtpk_bf16(float lo, float hi) {
  unsigned r;
  asm("v_cvt_pk_bf16_f32 %0, %1, %2" : "=v"(r) : "v"(lo), "v"(hi));
  return r;
}

__device__ __forceinline__ f32x16 mfma32(bf16x8 a, bf16x8 b, f32x16 c) {
  return __builtin_amdgcn_mfma_f32_32x32x16_bf16(a, b, c, 0, 0, 0);
}

__device__ __forceinline__ void gld16(unsigned short* lds, const unsigned short* g) {
  __builtin_amdgcn_global_load_lds(
      (const __attribute__((address_space(1))) unsigned int*)g,
      (__attribute__((address_space(3))) unsigned int*)lds, 16, 0, 0);
}

// ---------------- weights-only fp32 -> bf16 cast (1 launch) ----------------
__global__ __launch_bounds__(256)
void cast_w(const float* __restrict__ wq, const float* __restrict__ wk,
            const float* __restrict__ wv, const float* __restrict__ wo,
            unsigned short* __restrict__ wqb, unsigned short* __restrict__ wkb,
            unsigned short* __restrict__ wvb, unsigned short* __restrict__ wob) {
  constexpr int W4 = 1024 * 1024 / 4;   // 262,144 float4 units per weight
  const int i = blockIdx.x * 256 + threadIdx.x;
  const int r = i / W4;
  const int off = i - r * W4;
  const float* src = (r == 0) ? wq : (r == 1) ? wk : (r == 2) ? wv : wo;
  unsigned short* dst = (r == 0) ? wqb : (r == 1) ? wkb : (r == 2) ? wvb : wob;
  const float4 f = ((const float4*)src)[off];
  ushort4 o;
  o.x = f2bf(f.x); o.y = f2bf(f.y); o.z = f2bf(f.z); o.w = f2bf(f.w);
  ((ushort4*)dst)[off] = o;
}

// ---------------- GEMM: C[m,n] = sum_k A[m,k]*W[n,k] + bias[n] ----------------
// Flat 512-block grid, XCD-chunked decode (R11, verified): xcd=bid&7 owns
// M-panels [8*xcd, 8*xcd+8), N walked fastest -> A-panel reused from one L2.
// CASTA=true: A is fp32, staged via reg+cvt_pk+ds_write (same LDS layout).
// CASTA=false: A is bf16, staged via global_load_lds (byte-identical to R11).
template <bool F32OUT, bool SCALEQ, bool CASTA>
__global__ __launch_bounds__(256)
void gemm_bt(const void* __restrict__ Ap,
             const unsigned short* __restrict__ Bw,
             const float* __restrict__ bias,
             unsigned short* __restrict__ Cb,
             float* __restrict__ Cf,
             int M, int N, int K) {
  __shared__ unsigned short As[128 * 32];
  __shared__ unsigned short Bs[128 * 32];
  const int tid = threadIdx.x;
  const int lane = tid & 63;
  const int w = tid >> 6;
  const int wm = (w >> 1) * 64;
  const int wn = (w & 1) * 64;
  const int bid = blockIdx.x;
  const int xcd = bid & 7, jj = bid >> 3;
  const int m0 = (xcd * 8 + (jj >> 3)) * 128;
  const int n0 = (jj & 7) * 128;
  const int l15 = lane & 15, l4 = lane >> 4;

  const float* Af = (const float*)Ap;
  const unsigned short* Ab = (const unsigned short*)Ap;

  f32x4 acc[4][4] = {};

  const int c0 = tid, c1 = 256 + tid;
  const int r0 = c0 >> 2, kc0 = (c0 & 3) * 8;
  const int r1 = c1 >> 2, kc1 = (c1 & 3) * 8;

  for (int k0 = 0; k0 < K; k0 += 32) {
    if constexpr (CASTA) {
      // issue fp32 A loads BEFORE the barrier (no LDS hazard; latency hidden)
      const float4* a0p = (const float4*)(Af + (size_t)(m0 + r0) * K + k0 + kc0);
      const float4* a1p = (const float4*)(Af + (size_t)(m0 + r1) * K + k0 + kc1);
      const float4 a00 = a0p[0], a01 = a0p[1];
      const float4 a10 = a1p[0], a11 = a1p[1];
      __syncthreads();  // previous tile's LDS reads done
      union { bf16x8 v; unsigned u[4]; } p0, p1;
      p0.u[0] = cvtpk_bf16(a00.x, a00.y); p0.u[1] = cvtpk_bf16(a00.z, a00.w);
      p0.u[2] = cvtpk_bf16(a01.x, a01.y); p0.u[3] = cvtpk_bf16(a01.z, a01.w);
      p1.u[0] = cvtpk_bf16(a10.x, a10.y); p1.u[1] = cvtpk_bf16(a10.z, a10.w);
      p1.u[2] = cvtpk_bf16(a11.x, a11.y); p1.u[3] = cvtpk_bf16(a11.z, a11.w);
      *(bf16x8*)&As[c0 * 8] = p0.v;
      *(bf16x8*)&As[c1 * 8] = p1.v;
      gld16(&Bs[c0 * 8], &Bw[(size_t)(n0 + r0) * K + k0 + kc0]);
      gld16(&Bs[c1 * 8], &Bw[(size_t)(n0 + r1) * K + k0 + kc1]);
      __syncthreads();  // publish A writes; drain B gld (vmcnt before barrier)
    } else {
      __syncthreads();
      gld16(&As[c0 * 8], &Ab[(size_t)(m0 + r0) * K + k0 + kc0]);
      gld16(&As[c1 * 8], &Ab[(size_t)(m0 + r1) * K + k0 + kc1]);
      gld16(&Bs[c0 * 8], &Bw[(size_t)(n0 + r0) * K + k0 + kc0]);
      gld16(&Bs[c1 * 8], &Bw[(size_t)(n0 + r1) * K + k0 + kc1]);
      __syncthreads();
    }

    bf16x8 af[4], bfr[4];
#pragma unroll
    for (int m = 0; m < 4; ++m)
      af[m] = *(const bf16x8*)&As[(wm + m * 16 + l15) * 32 + l4 * 8];
#pragma unroll
    for (int n = 0; n < 4; ++n)
      bfr[n] = *(const bf16x8*)&Bs[(wn + n * 16 + l15) * 32 + l4 * 8];
#pragma unroll
    for (int m = 0; m < 4; ++m)
#pragma unroll
      for (int n = 0; n < 4; ++n)
        acc[m][n] = __builtin_amdgcn_mfma_f32_16x16x32_bf16(af[m], bfr[n], acc[m][n], 0, 0, 0);
  }

  const int crow = l4 * 4;
#pragma unroll
  for (int m = 0; m < 4; ++m) {
#pragma unroll
    for (int n = 0; n < 4; ++n) {
      const int col = n0 + wn + n * 16 + l15;
      const float bv_ = bias[col];
#pragma unroll
      for (int j = 0; j < 4; ++j) {
        const int row = m0 + wm + m * 16 + crow + j;
        float v = acc[m][n][j] + bv_;
        if constexpr (SCALEQ) v *= 0.125f * 1.44269504f;  // 1/sqrt(dk) * log2(e)
        if constexpr (F32OUT) Cf[(size_t)row * N + col] = v;
        else                  Cb[(size_t)row * N + col] = f2bf(v);
      }
    }
  }
}

// ---------------- V transpose: [b,s,h*64+d] -> [(b*16+h)*64+d, s] ----------------
__global__ __launch_bounds__(256)
void transpose_v(const unsigned short* __restrict__ Vp, unsigned short* __restrict__ Vt) {
  constexpr int S = 2048, Dm = 1024;
  __shared__ __align__(16) unsigned short t[64][72];
  const int bh = blockIdx.x, b = bh >> 4, h = bh & 15;
  const int s0 = blockIdx.y * 64;
  const int tid = threadIdx.x;
#pragma unroll
  for (int r = 0; r < 2; ++r) {
    const int c = r * 256 + tid;
    const int sl = c >> 3, d8 = (c & 7) * 8;
    *(bf16x8*)&t[sl][d8] =
        *(const bf16x8*)&Vp[(size_t)(b * S + s0 + sl) * Dm + h * 64 + d8];
  }
  __syncthreads();
#pragma unroll
  for (int r = 0; r < 2; ++r) {
    const int c = r * 256 + tid;
    const int dl = c >> 3, s8 = (c & 7) * 8;
    bf16x8 ov;
#pragma unroll
    for (int jj = 0; jj < 8; ++jj) ov[jj] = t[s8 + jj][dl];
    *(bf16x8*)&Vt[(size_t)(bh * 64 + dl) * S + s0 + s8] = ov;
  }
}

// ---------------- flash attention, causal, cooperative 4-wave blocks ----------------
// FROZEN: byte-identical to R6/R10/R11 (passed three times).
__global__ __launch_bounds__(256)
void attn_fwd32b(const unsigned short* __restrict__ Qp,   // [B*S,1024] bf16 (scaled)
                 const unsigned short* __restrict__ Kp,   // [B*S,1024] bf16
                 const unsigned short* __restrict__ Vt,   // [(b*16+h)*64+d, S] bf16
                 unsigned short* __restrict__ Xo) {       // [B*S,1024] bf16
  constexpr int S = 2048, Dm = 1024;
  const int bh = blockIdx.x & 63;
  const int g  = 15 - (int)(blockIdx.x >> 6);   // longest blocks first
  const int b = bh >> 4, h = bh & 15;
  const int w = threadIdx.x >> 6;
  const int lane = threadIdx.x & 63;
  const int l31 = lane & 31, hi = lane >> 5;
  const int qb = 4 * g + w;
  const int qrow = qb * 32 + l31;
  const int ntw = qb + 1;          // this wave's KV tiles; tile ntw-1 masked
  const int NT = 4 * g + 4;        // uniform block trip count (even)

  // Q B-frags: col=q=l31, k(d)=c*16+hi*8
  const unsigned short* qptr = Qp + (size_t)(b * S + qrow) * Dm + h * 64 + hi * 8;
  bf16x8 qf[4];
#pragma unroll
  for (int c = 0; c < 4; ++c) qf[c] = *(const bf16x8*)(qptr + c * 16);

  const unsigned short* kbase = Kp + (size_t)(b * S) * Dm + h * 64 + hi * 8;
  const unsigned short* vr0 = Vt + (size_t)(bh * 64 + l31) * S + hi * 8;
  const unsigned short* vr1 = vr0 + (size_t)32 * S;

  f32x16 ot0 = {}, ot1 = {};   // O^T: rows d (0-31 / 32-63), col q=l31
  float m = -1e30f, l = 0.f;

  auto loadK = [&](bf16x8 (&kr)[4], int t) {
    const unsigned short* krow = kbase + (size_t)(t * 32 + l31) * Dm;
#pragma unroll
    for (int c = 0; c < 4; ++c) kr[c] = *(const bf16x8*)(krow + c * 16);
  };

  auto body = [&](bf16x8 (&kr)[4], int t) {
    const int kv0 = t * 32;
    // V loads issued early; consumed after softmax
    const bf16x8 vf0a = *(const bf16x8*)(vr0 + kv0);
    const bf16x8 vf0b = *(const bf16x8*)(vr0 + kv0 + 16);
    const bf16x8 vf1a = *(const bf16x8*)(vr1 + kv0);
    const bf16x8 vf1b = *(const bf16x8*)(vr1 + kv0 + 16);
    // S^T = K · Q  (rows kv, col q)
    f32x16 ts = {};
#pragma unroll
    for (int c = 0; c < 4; ++c) ts = mfma32(kr[c], qf[c], ts);
    if (t == ntw - 1) {   // diagonal tile
#pragma unroll
      for (int r = 0; r < 16; ++r) {
        const int kvp = kv0 + (r & 3) + 8 * (r >> 2) + 4 * hi;
        if (kvp > qrow) ts[r] = -1e9f;
      }
    }
    // row max: lane-local + 1 cross-half shfl
    float pmax = ts[0];
#pragma unroll
    for (int r = 1; r < 16; ++r) pmax = fmaxf(pmax, ts[r]);
    pmax = fmaxf(pmax, __shfl_xor(pmax, 32));
    // deferred rescale (T13; log2 units)
    if (__any(pmax > m + 11.5f)) {
      const float mn = (pmax > m + 11.5f) ? pmax : m;
      const float fct = __builtin_amdgcn_exp2f(m - mn);
      m = mn; l *= fct;
#pragma unroll
      for (int r = 0; r < 16; ++r) { ot0[r] *= fct; ot1[r] *= fct; }
    }
    // p = 2^(s-m), row-sum
    float p[16], ls = 0.f;
#pragma unroll
    for (int r = 0; r < 16; ++r) {
      p[r] = __builtin_amdgcn_exp2f(ts[r] - m);
      ls += p[r];
    }
    ls += __shfl_xor(ls, 32);
    l += ls;
    // pack bf16 pairs + cross-half exchange -> P^T B-frags (k=kv)
    unsigned ua[8];
#pragma unroll
    for (int i = 0; i < 8; ++i) ua[i] = cvtpk_bf16(p[2 * i], p[2 * i + 1]);
    union FR { bf16x8 v; unsigned u[4]; } fr0, fr1;
    {
      unsigned sa = hi ? ua[0] : ua[2], sb = hi ? ua[1] : ua[3];
      unsigned xa = __shfl_xor(sa, 32), xb = __shfl_xor(sb, 32);
      fr0.u[0] = hi ? xa : ua[0]; fr0.u[1] = hi ? xb : ua[1];
      fr0.u[2] = hi ? ua[2] : xa; fr0.u[3] = hi ? ua[3] : xb;
      unsigned sc = hi ? ua[4] : ua[6], sd = hi ? ua[5] : ua[7];
      unsigned xc = __shfl_xor(sc, 32), xd = __shfl_xor(sd, 32);
      fr1.u[0] = hi ? xc : ua[4]; fr1.u[1] = hi ? xd : ua[5];
      fr1.u[2] = hi ? ua[6] : xc; fr1.u[3] = hi ? ua[7] : xd;
    }
    // O^T += V^T · P^T
    ot0 = mfma32(vf0a, fr0.v, ot0);
    ot0 = mfma32(vf0b, fr1.v, ot0);
    ot1 = mfma32(vf1a, fr0.v, ot1);
    ot1 = mfma32(vf1b, fr1.v, ot1);
  };

  // ping-pong K prefetch; identical loads across the 4 waves (L1-shared).
  bf16x8 kA[4], kB[4];
  loadK(kA, 0);
  for (int t = 0; t < NT; t += 2) {
    loadK(kB, t + 1);
    if (t < ntw) body(kA, t);
    __builtin_amdgcn_s_barrier();
    const int t2 = (t + 2 < NT) ? (t + 2) : (NT - 1);  // clamped (redundant on last)
    loadK(kA, t2);
    if (t + 1 < ntw) body(kB, t + 1);
    __builtin_amdgcn_s_barrier();
  }

  // epilogue: normalize (lane-local l), pack pairs, 8B stores
  const float inv = 1.f / l;
  unsigned short* orow = Xo + (size_t)(b * S + qrow) * Dm + h * 64;
#pragma unroll
  for (int rq = 0; rq < 4; ++rq) {
    uint2 pr;
    pr.x = cvtpk_bf16(ot0[4 * rq + 0] * inv, ot0[4 * rq + 1] * inv);
    pr.y = cvtpk_bf16(ot0[4 * rq + 2] * inv, ot0[4 * rq + 3] * inv);
    *(uint2*)(orow + 8 * rq + 4 * hi) = pr;
    uint2 pr1;
    pr1.x = cvtpk_bf16(ot1[4 * rq + 0] * inv, ot1[4 * rq + 1] * inv);
    pr1.y = cvtpk_bf16(ot1[4 * rq + 2] * inv, ot1[4 * rq + 3] * inv);
    *(uint2*)(orow + 32 + 8 * rq + 4 * hi) = pr1;
  }
}

// ---------------- launch ----------------
extern "C" void kernel_launch(void* const* d_in, const int* in_sizes, int n_in,
                              void* d_out, int out_size, void* d_ws, size_t ws_size,
                              hipStream_t stream) {
  const float* query = (const float*)d_in[0];
  const float* key   = (const float*)d_in[1];
  const float* value = (const float*)d_in[2];
  const float* Wq = (const float*)d_in[4];
  const float* bq = (const float*)d_in[5];
  const float* Wk = (const float*)d_in[6];
  const float* bk = (const float*)d_in[7];
  const float* Wv = (const float*)d_in[8];
  const float* bv = (const float*)d_in[9];
  const float* Wo = (const float*)d_in[10];
  const float* bo = (const float*)d_in[11];

  constexpr int B = 4, S = 2048, D = 1024;
  constexpr int M = B * S;
  const size_t MB = 1024u * 1024u;
  uint8_t* ws = (uint8_t*)d_ws;

  unsigned short* Wqb = (unsigned short*)(ws + 48 * MB);
  unsigned short* Wkb = (unsigned short*)(ws + 50 * MB);
  unsigned short* Wvb = (unsigned short*)(ws + 52 * MB);
  unsigned short* Wob = (unsigned short*)(ws + 54 * MB);
  unsigned short* Qp  = (unsigned short*)(ws + 56 * MB);
  unsigned short* Kp  = (unsigned short*)(ws + 72 * MB);
  unsigned short* Vp  = (unsigned short*)(ws + 0);
  unsigned short* Vt  = (unsigned short*)(ws + 32 * MB);
  unsigned short* Xat = (unsigned short*)(ws + 16 * MB);

  // weights-only cast: 4*W4 float4 units
  constexpr int W4 = D * D / 4;
  cast_w<<<4 * W4 / 256, 256, 0, stream>>>(Wq, Wk, Wv, Wo, Wqb, Wkb, Wvb, Wob);

  // projections: A staged fp32->bf16 in-kernel (CASTA=true)
  gemm_bt<false, true , true ><<<512, 256, 0, stream>>>(query, Wqb, bq, Qp, nullptr, M, D, D);
  gemm_bt<false, false, true ><<<512, 256, 0, stream>>>(key,   Wkb, bk, Kp, nullptr, M, D, D);
  gemm_bt<false, false, true ><<<512, 256, 0, stream>>>(value, Wvb, bv, Vp, nullptr, M, D, D);

  transpose_v<<<dim3(64, S / 64), 256, 0, stream>>>(Vp, Vt);

  attn_fwd32b<<<1024, 256, 0, stream>>>(Qp, Kp, Vt, Xat);

  // output projection: A already bf16 (CASTA=false, staging identical to R11)
  gemm_bt<true, false, false><<<512, 256, 0, stream>>>(Xat, Wob, bo, nullptr, (float*)d_out, M, D, D);
}

// Round 14
// 266.878 us; speedup vs baseline: 1.1332x; 1.0228x over previous
//
#include <hip/hip_runtime.h>
#include <cstdint>
#include <cstddef>

// MHA: out = softmax_causal((XqWq^T+bq)(XkWk^T+bk)^T / 8) (XvWv^T+bv) Wo^T + bo
// B=4 S=2048 D=1024 H=16 dk=64. bf16 MFMA, fp32 accum. exp2-domain softmax
// (Q projection pre-scaled by 0.125*log2(e)).
// R13: transpose_v DELETED -- V-GEMM epilogue (TRANSV=true) writes the
// transposed layout Vt[(b*16+h)*64+d][s] directly (index remap + packed 8B
// stores; numerics identical). Saves ~32MB of pure relayout traffic.
// attn frozen (= R6/R10/R11/R12, passed 4x). Other GEMMs byte-identical to R12.

typedef __attribute__((ext_vector_type(8))) short bf16x8;
typedef __attribute__((ext_vector_type(4))) float f32x4;
typedef __attribute__((ext_vector_type(16))) float f32x16;

__device__ __forceinline__ unsigned short f2bf(float f) {
  union { float f; unsigned u; } x; x.f = f;
  unsigned r = x.u + 0x7FFFu + ((x.u >> 16) & 1u);   // RNE
  return (unsigned short)(r >> 16);
}

__device__ __forceinline__ unsigned cvtpk_bf16(float lo, float hi) {
  unsigned r;
  asm("v_cvt_pk_bf16_f32 %0, %1, %2" : "=v"(r) : "v"(lo), "v"(hi));
  return r;
}

__device__ __forceinline__ f32x16 mfma32(bf16x8 a, bf16x8 b, f32x16 c) {
  return __builtin_amdgcn_mfma_f32_32x32x16_bf16(a, b, c, 0, 0, 0);
}

__device__ __forceinline__ void gld16(unsigned short* lds, const unsigned short* g) {
  __builtin_amdgcn_global_load_lds(
      (const __attribute__((address_space(1))) unsigned int*)g,
      (__attribute__((address_space(3))) unsigned int*)lds, 16, 0, 0);
}

// ---------------- weights-only fp32 -> bf16 cast (1 launch) ----------------
__global__ __launch_bounds__(256)
void cast_w(const float* __restrict__ wq, const float* __restrict__ wk,
            const float* __restrict__ wv, const float* __restrict__ wo,
            unsigned short* __restrict__ wqb, unsigned short* __restrict__ wkb,
            unsigned short* __restrict__ wvb, unsigned short* __restrict__ wob) {
  constexpr int W4 = 1024 * 1024 / 4;   // 262,144 float4 units per weight
  const int i = blockIdx.x * 256 + threadIdx.x;
  const int r = i / W4;
  const int off = i - r * W4;
  const float* src = (r == 0) ? wq : (r == 1) ? wk : (r == 2) ? wv : wo;
  unsigned short* dst = (r == 0) ? wqb : (r == 1) ? wkb : (r == 2) ? wvb : wob;
  const float4 f = ((const float4*)src)[off];
  ushort4 o;
  o.x = f2bf(f.x); o.y = f2bf(f.y); o.z = f2bf(f.z); o.w = f2bf(f.w);
  ((ushort4*)dst)[off] = o;
}

// ---------------- GEMM: C[m,n] = sum_k A[m,k]*W[n,k] + bias[n] ----------------
// Flat 512-block grid, XCD-chunked decode (R11, verified). CASTA (R12,
// verified): A staged fp32->reg->cvt_pk->ds_write, same LDS layout.
// TRANSV: epilogue writes Vt[(b*16+h)*64+d][s] (s = row & 2047, b = row>>11,
// h = col>>6, d = col&63), 4 consecutive s packed per 8B store.
template <bool F32OUT, bool SCALEQ, bool CASTA, bool TRANSV>
__global__ __launch_bounds__(256)
void gemm_bt(const void* __restrict__ Ap,
             const unsigned short* __restrict__ Bw,
             const float* __restrict__ bias,
             unsigned short* __restrict__ Cb,
             float* __restrict__ Cf,
             int M, int N, int K) {
  __shared__ unsigned short As[128 * 32];
  __shared__ unsigned short Bs[128 * 32];
  const int tid = threadIdx.x;
  const int lane = tid & 63;
  const int w = tid >> 6;
  const int wm = (w >> 1) * 64;
  const int wn = (w & 1) * 64;
  const int bid = blockIdx.x;
  const int xcd = bid & 7, jj = bid >> 3;
  const int m0 = (xcd * 8 + (jj >> 3)) * 128;
  const int n0 = (jj & 7) * 128;
  const int l15 = lane & 15, l4 = lane >> 4;

  const float* Af = (const float*)Ap;
  const unsigned short* Ab = (const unsigned short*)Ap;

  f32x4 acc[4][4] = {};

  const int c0 = tid, c1 = 256 + tid;
  const int r0 = c0 >> 2, kc0 = (c0 & 3) * 8;
  const int r1 = c1 >> 2, kc1 = (c1 & 3) * 8;

  for (int k0 = 0; k0 < K; k0 += 32) {
    if constexpr (CASTA) {
      // issue fp32 A loads BEFORE the barrier (no LDS hazard; latency hidden)
      const float4* a0p = (const float4*)(Af + (size_t)(m0 + r0) * K + k0 + kc0);
      const float4* a1p = (const float4*)(Af + (size_t)(m0 + r1) * K + k0 + kc1);
      const float4 a00 = a0p[0], a01 = a0p[1];
      const float4 a10 = a1p[0], a11 = a1p[1];
      __syncthreads();  // previous tile's LDS reads done
      union { bf16x8 v; unsigned u[4]; } p0, p1;
      p0.u[0] = cvtpk_bf16(a00.x, a00.y); p0.u[1] = cvtpk_bf16(a00.z, a00.w);
      p0.u[2] = cvtpk_bf16(a01.x, a01.y); p0.u[3] = cvtpk_bf16(a01.z, a01.w);
      p1.u[0] = cvtpk_bf16(a10.x, a10.y); p1.u[1] = cvtpk_bf16(a10.z, a10.w);
      p1.u[2] = cvtpk_bf16(a11.x, a11.y); p1.u[3] = cvtpk_bf16(a11.z, a11.w);
      *(bf16x8*)&As[c0 * 8] = p0.v;
      *(bf16x8*)&As[c1 * 8] = p1.v;
      gld16(&Bs[c0 * 8], &Bw[(size_t)(n0 + r0) * K + k0 + kc0]);
      gld16(&Bs[c1 * 8], &Bw[(size_t)(n0 + r1) * K + k0 + kc1]);
      __syncthreads();  // publish A writes; drain B gld (vmcnt before barrier)
    } else {
      __syncthreads();
      gld16(&As[c0 * 8], &Ab[(size_t)(m0 + r0) * K + k0 + kc0]);
      gld16(&As[c1 * 8], &Ab[(size_t)(m0 + r1) * K + k0 + kc1]);
      gld16(&Bs[c0 * 8], &Bw[(size_t)(n0 + r0) * K + k0 + kc0]);
      gld16(&Bs[c1 * 8], &Bw[(size_t)(n0 + r1) * K + k0 + kc1]);
      __syncthreads();
    }

    bf16x8 af[4], bfr[4];
#pragma unroll
    for (int m = 0; m < 4; ++m)
      af[m] = *(const bf16x8*)&As[(wm + m * 16 + l15) * 32 + l4 * 8];
#pragma unroll
    for (int n = 0; n < 4; ++n)
      bfr[n] = *(const bf16x8*)&Bs[(wn + n * 16 + l15) * 32 + l4 * 8];
#pragma unroll
    for (int m = 0; m < 4; ++m)
#pragma unroll
      for (int n = 0; n < 4; ++n)
        acc[m][n] = __builtin_amdgcn_mfma_f32_16x16x32_bf16(af[m], bfr[n], acc[m][n], 0, 0, 0);
  }

  const int crow = l4 * 4;
#pragma unroll
  for (int m = 0; m < 4; ++m) {
#pragma unroll
    for (int n = 0; n < 4; ++n) {
      const int col = n0 + wn + n * 16 + l15;
      const float bv_ = bias[col];
      if constexpr (TRANSV) {
        // rows m0+wm+m*16+crow+j, j=0..3: 4 consecutive s at fixed (b,h,d)
        constexpr int SS = 2048;
        const int rowb = m0 + wm + m * 16 + crow;      // multiple of 4
        const int b_ = rowb >> 11, s_ = rowb & (SS - 1);
        const int vrow = ((b_ << 4) + (col >> 6)) * 64 + (col & 63);
        uint2 pk;
        pk.x = cvtpk_bf16(acc[m][n][0] + bv_, acc[m][n][1] + bv_);
        pk.y = cvtpk_bf16(acc[m][n][2] + bv_, acc[m][n][3] + bv_);
        *(uint2*)&Cb[(size_t)vrow * SS + s_] = pk;
      } else {
#pragma unroll
        for (int j = 0; j < 4; ++j) {
          const int row = m0 + wm + m * 16 + crow + j;
          float v = acc[m][n][j] + bv_;
          if constexpr (SCALEQ) v *= 0.125f * 1.44269504f;  // 1/sqrt(dk)*log2(e)
          if constexpr (F32OUT) Cf[(size_t)row * N + col] = v;
          else                  Cb[(size_t)row * N + col] = f2bf(v);
        }
      }
    }
  }
}

// ---------------- flash attention, causal, cooperative 4-wave blocks ----------------
// FROZEN: byte-identical to R6/R10/R11/R12 (passed four times).
__global__ __launch_bounds__(256)
void attn_fwd32b(const unsigned short* __restrict__ Qp,   // [B*S,1024] bf16 (scaled)
                 const unsigned short* __restrict__ Kp,   // [B*S,1024] bf16
                 const unsigned short* __restrict__ Vt,   // [(b*16+h)*64+d, S] bf16
                 unsigned short* __restrict__ Xo) {       // [B*S,1024] bf16
  constexpr int S = 2048, Dm = 1024;
  const int bh = blockIdx.x & 63;
  const int g  = 15 - (int)(blockIdx.x >> 6);   // longest blocks first
  const int b = bh >> 4, h = bh & 15;
  const int w = threadIdx.x >> 6;
  const int lane = threadIdx.x & 63;
  const int l31 = lane & 31, hi = lane >> 5;
  const int qb = 4 * g + w;
  const int qrow = qb * 32 + l31;
  const int ntw = qb + 1;          // this wave's KV tiles; tile ntw-1 masked
  const int NT = 4 * g + 4;        // uniform block trip count (even)

  // Q B-frags: col=q=l31, k(d)=c*16+hi*8
  const unsigned short* qptr = Qp + (size_t)(b * S + qrow) * Dm + h * 64 + hi * 8;
  bf16x8 qf[4];
#pragma unroll
  for (int c = 0; c < 4; ++c) qf[c] = *(const bf16x8*)(qptr + c * 16);

  const unsigned short* kbase = Kp + (size_t)(b * S) * Dm + h * 64 + hi * 8;
  const unsigned short* vr0 = Vt + (size_t)(bh * 64 + l31) * S + hi * 8;
  const unsigned short* vr1 = vr0 + (size_t)32 * S;

  f32x16 ot0 = {}, ot1 = {};   // O^T: rows d (0-31 / 32-63), col q=l31
  float m = -1e30f, l = 0.f;

  auto loadK = [&](bf16x8 (&kr)[4], int t) {
    const unsigned short* krow = kbase + (size_t)(t * 32 + l31) * Dm;
#pragma unroll
    for (int c = 0; c < 4; ++c) kr[c] = *(const bf16x8*)(krow + c * 16);
  };

  auto body = [&](bf16x8 (&kr)[4], int t) {
    const int kv0 = t * 32;
    // V loads issued early; consumed after softmax
    const bf16x8 vf0a = *(const bf16x8*)(vr0 + kv0);
    const bf16x8 vf0b = *(const bf16x8*)(vr0 + kv0 + 16);
    const bf16x8 vf1a = *(const bf16x8*)(vr1 + kv0);
    const bf16x8 vf1b = *(const bf16x8*)(vr1 + kv0 + 16);
    // S^T = K · Q  (rows kv, col q)
    f32x16 ts = {};
#pragma unroll
    for (int c = 0; c < 4; ++c) ts = mfma32(kr[c], qf[c], ts);
    if (t == ntw - 1) {   // diagonal tile
#pragma unroll
      for (int r = 0; r < 16; ++r) {
        const int kvp = kv0 + (r & 3) + 8 * (r >> 2) + 4 * hi;
        if (kvp > qrow) ts[r] = -1e9f;
      }
    }
    // row max: lane-local + 1 cross-half shfl
    float pmax = ts[0];
#pragma unroll
    for (int r = 1; r < 16; ++r) pmax = fmaxf(pmax, ts[r]);
    pmax = fmaxf(pmax, __shfl_xor(pmax, 32));
    // deferred rescale (T13; log2 units)
    if (__any(pmax > m + 11.5f)) {
      const float mn = (pmax > m + 11.5f) ? pmax : m;
      const float fct = __builtin_amdgcn_exp2f(m - mn);
      m = mn; l *= fct;
#pragma unroll
      for (int r = 0; r < 16; ++r) { ot0[r] *= fct; ot1[r] *= fct; }
    }
    // p = 2^(s-m), row-sum
    float p[16], ls = 0.f;
#pragma unroll
    for (int r = 0; r < 16; ++r) {
      p[r] = __builtin_amdgcn_exp2f(ts[r] - m);
      ls += p[r];
    }
    ls += __shfl_xor(ls, 32);
    l += ls;
    // pack bf16 pairs + cross-half exchange -> P^T B-frags (k=kv)
    unsigned ua[8];
#pragma unroll
    for (int i = 0; i < 8; ++i) ua[i] = cvtpk_bf16(p[2 * i], p[2 * i + 1]);
    union FR { bf16x8 v; unsigned u[4]; } fr0, fr1;
    {
      unsigned sa = hi ? ua[0] : ua[2], sb = hi ? ua[1] : ua[3];
      unsigned xa = __shfl_xor(sa, 32), xb = __shfl_xor(sb, 32);
      fr0.u[0] = hi ? xa : ua[0]; fr0.u[1] = hi ? xb : ua[1];
      fr0.u[2] = hi ? ua[2] : xa; fr0.u[3] = hi ? ua[3] : xb;
      unsigned sc = hi ? ua[4] : ua[6], sd = hi ? ua[5] : ua[7];
      unsigned xc = __shfl_xor(sc, 32), xd = __shfl_xor(sd, 32);
      fr1.u[0] = hi ? xc : ua[4]; fr1.u[1] = hi ? xd : ua[5];
      fr1.u[2] = hi ? ua[6] : xc; fr1.u[3] = hi ? ua[7] : xd;
    }
    // O^T += V^T · P^T
    ot0 = mfma32(vf0a, fr0.v, ot0);
    ot0 = mfma32(vf0b, fr1.v, ot0);
    ot1 = mfma32(vf1a, fr0.v, ot1);
    ot1 = mfma32(vf1b, fr1.v, ot1);
  };

  // ping-pong K prefetch; identical loads across the 4 waves (L1-shared).
  bf16x8 kA[4], kB[4];
  loadK(kA, 0);
  for (int t = 0; t < NT; t += 2) {
    loadK(kB, t + 1);
    if (t < ntw) body(kA, t);
    __builtin_amdgcn_s_barrier();
    const int t2 = (t + 2 < NT) ? (t + 2) : (NT - 1);  // clamped (redundant on last)
    loadK(kA, t2);
    if (t + 1 < ntw) body(kB, t + 1);
    __builtin_amdgcn_s_barrier();
  }

  // epilogue: normalize (lane-local l), pack pairs, 8B stores
  const float inv = 1.f / l;
  unsigned short* orow = Xo + (size_t)(b * S + qrow) * Dm + h * 64;
#pragma unroll
  for (int rq = 0; rq < 4; ++rq) {
    uint2 pr;
    pr.x = cvtpk_bf16(ot0[4 * rq + 0] * inv, ot0[4 * rq + 1] * inv);
    pr.y = cvtpk_bf16(ot0[4 * rq + 2] * inv, ot0[4 * rq + 3] * inv);
    *(uint2*)(orow + 8 * rq + 4 * hi) = pr;
    uint2 pr1;
    pr1.x = cvtpk_bf16(ot1[4 * rq + 0] * inv, ot1[4 * rq + 1] * inv);
    pr1.y = cvtpk_bf16(ot1[4 * rq + 2] * inv, ot1[4 * rq + 3] * inv);
    *(uint2*)(orow + 32 + 8 * rq + 4 * hi) = pr1;
  }
}

// ---------------- launch ----------------
extern "C" void kernel_launch(void* const* d_in, const int* in_sizes, int n_in,
                              void* d_out, int out_size, void* d_ws, size_t ws_size,
                              hipStream_t stream) {
  const float* query = (const float*)d_in[0];
  const float* key   = (const float*)d_in[1];
  const float* value = (const float*)d_in[2];
  const float* Wq = (const float*)d_in[4];
  const float* bq = (const float*)d_in[5];
  const float* Wk = (const float*)d_in[6];
  const float* bk = (const float*)d_in[7];
  const float* Wv = (const float*)d_in[8];
  const float* bv = (const float*)d_in[9];
  const float* Wo = (const float*)d_in[10];
  const float* bo = (const float*)d_in[11];

  constexpr int B = 4, S = 2048, D = 1024;
  constexpr int M = B * S;
  const size_t MB = 1024u * 1024u;
  uint8_t* ws = (uint8_t*)d_ws;

  unsigned short* Wqb = (unsigned short*)(ws + 48 * MB);
  unsigned short* Wkb = (unsigned short*)(ws + 50 * MB);
  unsigned short* Wvb = (unsigned short*)(ws + 52 * MB);
  unsigned short* Wob = (unsigned short*)(ws + 54 * MB);
  unsigned short* Qp  = (unsigned short*)(ws + 56 * MB);
  unsigned short* Kp  = (unsigned short*)(ws + 72 * MB);
  unsigned short* Vt  = (unsigned short*)(ws + 32 * MB);
  unsigned short* Xat = (unsigned short*)(ws + 16 * MB);

  // weights-only cast: 4*W4 float4 units
  constexpr int W4 = D * D / 4;
  cast_w<<<4 * W4 / 256, 256, 0, stream>>>(Wq, Wk, Wv, Wo, Wqb, Wkb, Wvb, Wob);

  // projections: A staged fp32->bf16 in-kernel (CASTA=true);
  // V-GEMM writes transposed Vt directly (TRANSV=true) -> no transpose pass
  gemm_bt<false, true , true , false><<<512, 256, 0, stream>>>(query, Wqb, bq, Qp, nullptr, M, D, D);
  gemm_bt<false, false, true , false><<<512, 256, 0, stream>>>(key,   Wkb, bk, Kp, nullptr, M, D, D);
  gemm_bt<false, false, true , true ><<<512, 256, 0, stream>>>(value, Wvb, bv, Vt, nullptr, M, D, D);

  attn_fwd32b<<<1024, 256, 0, stream>>>(Qp, Kp, Vt, Xat);

  // output projection: A already bf16 (CASTA=false, staging identical to R11)
  gemm_bt<true, false, false, false><<<512, 256, 0, stream>>>(Xat, Wob, bo, nullptr, (float*)d_out, M, D, D);
}

// Round 15
// 256.634 us; speedup vs baseline: 1.1784x; 1.0399x over previous
//
#include <hip/hip_runtime.h>
#include <cstdint>
#include <cstddef>

// MHA: out = softmax_causal((XqWq^T+bq)(XkWk^T+bk)^T / 8) (XvWv^T+bv) Wo^T + bo
// B=4 S=2048 D=1024 H=16 dk=64. bf16 MFMA, fp32 accum. exp2-domain softmax
// (Q projection pre-scaled by 0.125*log2(e)).
// R14: GEMM K-step widened to BK=64 (16 iterations instead of 32 -> half the
// vmcnt(0)+s_barrier drains). Same two-barrier hazard structure; 4 staging
// chunks/tensor/thread; LDS 32KB (2 blocks/CU -> 64KB used, no cliff).
// attn frozen (= R6/R10-R13, passed 5x). CASTA/TRANSV/XCD-decode as verified.

typedef __attribute__((ext_vector_type(8))) short bf16x8;
typedef __attribute__((ext_vector_type(4))) float f32x4;
typedef __attribute__((ext_vector_type(16))) float f32x16;

__device__ __forceinline__ unsigned short f2bf(float f) {
  union { float f; unsigned u; } x; x.f = f;
  unsigned r = x.u + 0x7FFFu + ((x.u >> 16) & 1u);   // RNE
  return (unsigned short)(r >> 16);
}

__device__ __forceinline__ unsigned cvtpk_bf16(float lo, float hi) {
  unsigned r;
  asm("v_cvt_pk_bf16_f32 %0, %1, %2" : "=v"(r) : "v"(lo), "v"(hi));
  return r;
}

__device__ __forceinline__ f32x16 mfma32(bf16x8 a, bf16x8 b, f32x16 c) {
  return __builtin_amdgcn_mfma_f32_32x32x16_bf16(a, b, c, 0, 0, 0);
}

__device__ __forceinline__ void gld16(unsigned short* lds, const unsigned short* g) {
  __builtin_amdgcn_global_load_lds(
      (const __attribute__((address_space(1))) unsigned int*)g,
      (__attribute__((address_space(3))) unsigned int*)lds, 16, 0, 0);
}

// ---------------- weights-only fp32 -> bf16 cast (1 launch) ----------------
__global__ __launch_bounds__(256)
void cast_w(const float* __restrict__ wq, const float* __restrict__ wk,
            const float* __restrict__ wv, const float* __restrict__ wo,
            unsigned short* __restrict__ wqb, unsigned short* __restrict__ wkb,
            unsigned short* __restrict__ wvb, unsigned short* __restrict__ wob) {
  constexpr int W4 = 1024 * 1024 / 4;   // 262,144 float4 units per weight
  const int i = blockIdx.x * 256 + threadIdx.x;
  const int r = i / W4;
  const int off = i - r * W4;
  const float* src = (r == 0) ? wq : (r == 1) ? wk : (r == 2) ? wv : wo;
  unsigned short* dst = (r == 0) ? wqb : (r == 1) ? wkb : (r == 2) ? wvb : wob;
  const float4 f = ((const float4*)src)[off];
  ushort4 o;
  o.x = f2bf(f.x); o.y = f2bf(f.y); o.z = f2bf(f.z); o.w = f2bf(f.w);
  ((ushort4*)dst)[off] = o;
}

// ---------------- GEMM: C[m,n] = sum_k A[m,k]*W[n,k] + bias[n] ----------------
// Flat 512-block grid, XCD-chunked decode (R11). CASTA (R12): A staged
// fp32->reg->cvt_pk->ds_write. TRANSV (R13): epilogue writes
// Vt[(b*16+h)*64+d][s] packed 8B. BK=64 (R14): 4 chunks/tensor/thread,
// inner kk=0,1 fragment+MFMA loop accumulating into the same acc.
template <bool F32OUT, bool SCALEQ, bool CASTA, bool TRANSV>
__global__ __launch_bounds__(256)
void gemm_bt(const void* __restrict__ Ap,
             const unsigned short* __restrict__ Bw,
             const float* __restrict__ bias,
             unsigned short* __restrict__ Cb,
             float* __restrict__ Cf,
             int M, int N, int K) {
  __shared__ unsigned short As[128 * 64];
  __shared__ unsigned short Bs[128 * 64];
  const int tid = threadIdx.x;
  const int lane = tid & 63;
  const int w = tid >> 6;
  const int wm = (w >> 1) * 64;
  const int wn = (w & 1) * 64;
  const int bid = blockIdx.x;
  const int xcd = bid & 7, jj = bid >> 3;
  const int m0 = (xcd * 8 + (jj >> 3)) * 128;
  const int n0 = (jj & 7) * 128;
  const int l15 = lane & 15, l4 = lane >> 4;

  const float* Af = (const float*)Ap;
  const unsigned short* Ab = (const unsigned short*)Ap;

  f32x4 acc[4][4] = {};

  for (int k0 = 0; k0 < K; k0 += 64) {
    if constexpr (CASTA) {
      // issue fp32 A loads BEFORE the barrier (no LDS hazard; latency hidden)
      float4 av[4][2];
#pragma unroll
      for (int q = 0; q < 4; ++q) {
        const int c = q * 256 + tid;
        const int row = c >> 3, kc = (c & 7) * 8;
        const float4* ap = (const float4*)(Af + (size_t)(m0 + row) * K + k0 + kc);
        av[q][0] = ap[0];
        av[q][1] = ap[1];
      }
      __syncthreads();  // previous tile's LDS reads done
#pragma unroll
      for (int q = 0; q < 4; ++q) {
        const int c = q * 256 + tid;
        union { bf16x8 v; unsigned u[4]; } p;
        p.u[0] = cvtpk_bf16(av[q][0].x, av[q][0].y);
        p.u[1] = cvtpk_bf16(av[q][0].z, av[q][0].w);
        p.u[2] = cvtpk_bf16(av[q][1].x, av[q][1].y);
        p.u[3] = cvtpk_bf16(av[q][1].z, av[q][1].w);
        *(bf16x8*)&As[c * 8] = p.v;
      }
#pragma unroll
      for (int q = 0; q < 4; ++q) {
        const int c = q * 256 + tid;
        const int row = c >> 3, kc = (c & 7) * 8;
        gld16(&Bs[c * 8], &Bw[(size_t)(n0 + row) * K + k0 + kc]);
      }
      __syncthreads();  // publish A writes; drain B gld
    } else {
      __syncthreads();
#pragma unroll
      for (int q = 0; q < 4; ++q) {
        const int c = q * 256 + tid;
        const int row = c >> 3, kc = (c & 7) * 8;
        gld16(&As[c * 8], &Ab[(size_t)(m0 + row) * K + k0 + kc]);
        gld16(&Bs[c * 8], &Bw[(size_t)(n0 + row) * K + k0 + kc]);
      }
      __syncthreads();
    }

#pragma unroll
    for (int kk = 0; kk < 2; ++kk) {
      bf16x8 af[4], bfr[4];
#pragma unroll
      for (int m = 0; m < 4; ++m)
        af[m] = *(const bf16x8*)&As[(wm + m * 16 + l15) * 64 + kk * 32 + l4 * 8];
#pragma unroll
      for (int n = 0; n < 4; ++n)
        bfr[n] = *(const bf16x8*)&Bs[(wn + n * 16 + l15) * 64 + kk * 32 + l4 * 8];
#pragma unroll
      for (int m = 0; m < 4; ++m)
#pragma unroll
        for (int n = 0; n < 4; ++n)
          acc[m][n] = __builtin_amdgcn_mfma_f32_16x16x32_bf16(af[m], bfr[n], acc[m][n], 0, 0, 0);
    }
  }

  const int crow = l4 * 4;
#pragma unroll
  for (int m = 0; m < 4; ++m) {
#pragma unroll
    for (int n = 0; n < 4; ++n) {
      const int col = n0 + wn + n * 16 + l15;
      const float bv_ = bias[col];
      if constexpr (TRANSV) {
        // rows m0+wm+m*16+crow+j, j=0..3: 4 consecutive s at fixed (b,h,d)
        constexpr int SS = 2048;
        const int rowb = m0 + wm + m * 16 + crow;      // multiple of 4
        const int b_ = rowb >> 11, s_ = rowb & (SS - 1);
        const int vrow = ((b_ << 4) + (col >> 6)) * 64 + (col & 63);
        uint2 pk;
        pk.x = cvtpk_bf16(acc[m][n][0] + bv_, acc[m][n][1] + bv_);
        pk.y = cvtpk_bf16(acc[m][n][2] + bv_, acc[m][n][3] + bv_);
        *(uint2*)&Cb[(size_t)vrow * SS + s_] = pk;
      } else {
#pragma unroll
        for (int j = 0; j < 4; ++j) {
          const int row = m0 + wm + m * 16 + crow + j;
          float v = acc[m][n][j] + bv_;
          if constexpr (SCALEQ) v *= 0.125f * 1.44269504f;  // 1/sqrt(dk)*log2(e)
          if constexpr (F32OUT) Cf[(size_t)row * N + col] = v;
          else                  Cb[(size_t)row * N + col] = f2bf(v);
        }
      }
    }
  }
}

// ---------------- flash attention, causal, cooperative 4-wave blocks ----------------
// FROZEN: byte-identical to R6/R10/R11/R12/R13 (passed five times).
__global__ __launch_bounds__(256)
void attn_fwd32b(const unsigned short* __restrict__ Qp,   // [B*S,1024] bf16 (scaled)
                 const unsigned short* __restrict__ Kp,   // [B*S,1024] bf16
                 const unsigned short* __restrict__ Vt,   // [(b*16+h)*64+d, S] bf16
                 unsigned short* __restrict__ Xo) {       // [B*S,1024] bf16
  constexpr int S = 2048, Dm = 1024;
  const int bh = blockIdx.x & 63;
  const int g  = 15 - (int)(blockIdx.x >> 6);   // longest blocks first
  const int b = bh >> 4, h = bh & 15;
  const int w = threadIdx.x >> 6;
  const int lane = threadIdx.x & 63;
  const int l31 = lane & 31, hi = lane >> 5;
  const int qb = 4 * g + w;
  const int qrow = qb * 32 + l31;
  const int ntw = qb + 1;          // this wave's KV tiles; tile ntw-1 masked
  const int NT = 4 * g + 4;        // uniform block trip count (even)

  // Q B-frags: col=q=l31, k(d)=c*16+hi*8
  const unsigned short* qptr = Qp + (size_t)(b * S + qrow) * Dm + h * 64 + hi * 8;
  bf16x8 qf[4];
#pragma unroll
  for (int c = 0; c < 4; ++c) qf[c] = *(const bf16x8*)(qptr + c * 16);

  const unsigned short* kbase = Kp + (size_t)(b * S) * Dm + h * 64 + hi * 8;
  const unsigned short* vr0 = Vt + (size_t)(bh * 64 + l31) * S + hi * 8;
  const unsigned short* vr1 = vr0 + (size_t)32 * S;

  f32x16 ot0 = {}, ot1 = {};   // O^T: rows d (0-31 / 32-63), col q=l31
  float m = -1e30f, l = 0.f;

  auto loadK = [&](bf16x8 (&kr)[4], int t) {
    const unsigned short* krow = kbase + (size_t)(t * 32 + l31) * Dm;
#pragma unroll
    for (int c = 0; c < 4; ++c) kr[c] = *(const bf16x8*)(krow + c * 16);
  };

  auto body = [&](bf16x8 (&kr)[4], int t) {
    const int kv0 = t * 32;
    // V loads issued early; consumed after softmax
    const bf16x8 vf0a = *(const bf16x8*)(vr0 + kv0);
    const bf16x8 vf0b = *(const bf16x8*)(vr0 + kv0 + 16);
    const bf16x8 vf1a = *(const bf16x8*)(vr1 + kv0);
    const bf16x8 vf1b = *(const bf16x8*)(vr1 + kv0 + 16);
    // S^T = K · Q  (rows kv, col q)
    f32x16 ts = {};
#pragma unroll
    for (int c = 0; c < 4; ++c) ts = mfma32(kr[c], qf[c], ts);
    if (t == ntw - 1) {   // diagonal tile
#pragma unroll
      for (int r = 0; r < 16; ++r) {
        const int kvp = kv0 + (r & 3) + 8 * (r >> 2) + 4 * hi;
        if (kvp > qrow) ts[r] = -1e9f;
      }
    }
    // row max: lane-local + 1 cross-half shfl
    float pmax = ts[0];
#pragma unroll
    for (int r = 1; r < 16; ++r) pmax = fmaxf(pmax, ts[r]);
    pmax = fmaxf(pmax, __shfl_xor(pmax, 32));
    // deferred rescale (T13; log2 units)
    if (__any(pmax > m + 11.5f)) {
      const float mn = (pmax > m + 11.5f) ? pmax : m;
      const float fct = __builtin_amdgcn_exp2f(m - mn);
      m = mn; l *= fct;
#pragma unroll
      for (int r = 0; r < 16; ++r) { ot0[r] *= fct; ot1[r] *= fct; }
    }
    // p = 2^(s-m), row-sum
    float p[16], ls = 0.f;
#pragma unroll
    for (int r = 0; r < 16; ++r) {
      p[r] = __builtin_amdgcn_exp2f(ts[r] - m);
      ls += p[r];
    }
    ls += __shfl_xor(ls, 32);
    l += ls;
    // pack bf16 pairs + cross-half exchange -> P^T B-frags (k=kv)
    unsigned ua[8];
#pragma unroll
    for (int i = 0; i < 8; ++i) ua[i] = cvtpk_bf16(p[2 * i], p[2 * i + 1]);
    union FR { bf16x8 v; unsigned u[4]; } fr0, fr1;
    {
      unsigned sa = hi ? ua[0] : ua[2], sb = hi ? ua[1] : ua[3];
      unsigned xa = __shfl_xor(sa, 32), xb = __shfl_xor(sb, 32);
      fr0.u[0] = hi ? xa : ua[0]; fr0.u[1] = hi ? xb : ua[1];
      fr0.u[2] = hi ? ua[2] : xa; fr0.u[3] = hi ? ua[3] : xb;
      unsigned sc = hi ? ua[4] : ua[6], sd = hi ? ua[5] : ua[7];
      unsigned xc = __shfl_xor(sc, 32), xd = __shfl_xor(sd, 32);
      fr1.u[0] = hi ? xc : ua[4]; fr1.u[1] = hi ? xd : ua[5];
      fr1.u[2] = hi ? ua[6] : xc; fr1.u[3] = hi ? ua[7] : xd;
    }
    // O^T += V^T · P^T
    ot0 = mfma32(vf0a, fr0.v, ot0);
    ot0 = mfma32(vf0b, fr1.v, ot0);
    ot1 = mfma32(vf1a, fr0.v, ot1);
    ot1 = mfma32(vf1b, fr1.v, ot1);
  };

  // ping-pong K prefetch; identical loads across the 4 waves (L1-shared).
  bf16x8 kA[4], kB[4];
  loadK(kA, 0);
  for (int t = 0; t < NT; t += 2) {
    loadK(kB, t + 1);
    if (t < ntw) body(kA, t);
    __builtin_amdgcn_s_barrier();
    const int t2 = (t + 2 < NT) ? (t + 2) : (NT - 1);  // clamped (redundant on last)
    loadK(kA, t2);
    if (t + 1 < ntw) body(kB, t + 1);
    __builtin_amdgcn_s_barrier();
  }

  // epilogue: normalize (lane-local l), pack pairs, 8B stores
  const float inv = 1.f / l;
  unsigned short* orow = Xo + (size_t)(b * S + qrow) * Dm + h * 64;
#pragma unroll
  for (int rq = 0; rq < 4; ++rq) {
    uint2 pr;
    pr.x = cvtpk_bf16(ot0[4 * rq + 0] * inv, ot0[4 * rq + 1] * inv);
    pr.y = cvtpk_bf16(ot0[4 * rq + 2] * inv, ot0[4 * rq + 3] * inv);
    *(uint2*)(orow + 8 * rq + 4 * hi) = pr;
    uint2 pr1;
    pr1.x = cvtpk_bf16(ot1[4 * rq + 0] * inv, ot1[4 * rq + 1] * inv);
    pr1.y = cvtpk_bf16(ot1[4 * rq + 2] * inv, ot1[4 * rq + 3] * inv);
    *(uint2*)(orow + 32 + 8 * rq + 4 * hi) = pr1;
  }
}

// ---------------- launch ----------------
extern "C" void kernel_launch(void* const* d_in, const int* in_sizes, int n_in,
                              void* d_out, int out_size, void* d_ws, size_t ws_size,
                              hipStream_t stream) {
  const float* query = (const float*)d_in[0];
  const float* key   = (const float*)d_in[1];
  const float* value = (const float*)d_in[2];
  const float* Wq = (const float*)d_in[4];
  const float* bq = (const float*)d_in[5];
  const float* Wk = (const float*)d_in[6];
  const float* bk = (const float*)d_in[7];
  const float* Wv = (const float*)d_in[8];
  const float* bv = (const float*)d_in[9];
  const float* Wo = (const float*)d_in[10];
  const float* bo = (const float*)d_in[11];

  constexpr int B = 4, S = 2048, D = 1024;
  constexpr int M = B * S;
  const size_t MB = 1024u * 1024u;
  uint8_t* ws = (uint8_t*)d_ws;

  unsigned short* Wqb = (unsigned short*)(ws + 48 * MB);
  unsigned short* Wkb = (unsigned short*)(ws + 50 * MB);
  unsigned short* Wvb = (unsigned short*)(ws + 52 * MB);
  unsigned short* Wob = (unsigned short*)(ws + 54 * MB);
  unsigned short* Qp  = (unsigned short*)(ws + 56 * MB);
  unsigned short* Kp  = (unsigned short*)(ws + 72 * MB);
  unsigned short* Vt  = (unsigned short*)(ws + 32 * MB);
  unsigned short* Xat = (unsigned short*)(ws + 16 * MB);

  // weights-only cast: 4*W4 float4 units
  constexpr int W4 = D * D / 4;
  cast_w<<<4 * W4 / 256, 256, 0, stream>>>(Wq, Wk, Wv, Wo, Wqb, Wkb, Wvb, Wob);

  // projections: A staged fp32->bf16 in-kernel (CASTA=true);
  // V-GEMM writes transposed Vt directly (TRANSV=true)
  gemm_bt<false, true , true , false><<<512, 256, 0, stream>>>(query, Wqb, bq, Qp, nullptr, M, D, D);
  gemm_bt<false, false, true , false><<<512, 256, 0, stream>>>(key,   Wkb, bk, Kp, nullptr, M, D, D);
  gemm_bt<false, false, true , true ><<<512, 256, 0, stream>>>(value, Wvb, bv, Vt, nullptr, M, D, D);

  attn_fwd32b<<<1024, 256, 0, stream>>>(Qp, Kp, Vt, Xat);

  // output projection: A already bf16 (CASTA=false)
  gemm_bt<true, false, false, false><<<512, 256, 0, stream>>>(Xat, Wob, bo, nullptr, (float*)d_out, M, D, D);
}

// Round 16
// 253.629 us; speedup vs baseline: 1.1924x; 1.0118x over previous
//
#include <hip/hip_runtime.h>
#include <cstdint>
#include <cstddef>

// MHA: out = softmax_causal((XqWq^T+bq)(XkWk^T+bk)^T / 8) (XvWv^T+bv) Wo^T + bo
// B=4 S=2048 D=1024 H=16 dk=64. bf16 MFMA, fp32 accum. exp2-domain softmax
// (Q projection pre-scaled by 0.125*log2(e)).
// R15: (1) attn MFMA clusters wrapped in s_setprio(1)/(0) (T5; pure scheduler
// hint, math/addresses/sync untouched). (2) Q/K/V projections merged into one
// 1536-block launch (which=bid>>9; K-loop byte-identical to verified BK=64
// CASTA path; SCALEQ/TRANSV now runtime epilogue branches).
// Verified stack: XCD-decode(R11) CASTA(R12) TRANSV(R13) BK=64(R14).

typedef __attribute__((ext_vector_type(8))) short bf16x8;
typedef __attribute__((ext_vector_type(4))) float f32x4;
typedef __attribute__((ext_vector_type(16))) float f32x16;

__device__ __forceinline__ unsigned short f2bf(float f) {
  union { float f; unsigned u; } x; x.f = f;
  unsigned r = x.u + 0x7FFFu + ((x.u >> 16) & 1u);   // RNE
  return (unsigned short)(r >> 16);
}

__device__ __forceinline__ unsigned cvtpk_bf16(float lo, float hi) {
  unsigned r;
  asm("v_cvt_pk_bf16_f32 %0, %1, %2" : "=v"(r) : "v"(lo), "v"(hi));
  return r;
}

__device__ __forceinline__ f32x16 mfma32(bf16x8 a, bf16x8 b, f32x16 c) {
  return __builtin_amdgcn_mfma_f32_32x32x16_bf16(a, b, c, 0, 0, 0);
}

__device__ __forceinline__ void gld16(unsigned short* lds, const unsigned short* g) {
  __builtin_amdgcn_global_load_lds(
      (const __attribute__((address_space(1))) unsigned int*)g,
      (__attribute__((address_space(3))) unsigned int*)lds, 16, 0, 0);
}

// ---------------- weights-only fp32 -> bf16 cast (1 launch) ----------------
__global__ __launch_bounds__(256)
void cast_w(const float* __restrict__ wq, const float* __restrict__ wk,
            const float* __restrict__ wv, const float* __restrict__ wo,
            unsigned short* __restrict__ wqb, unsigned short* __restrict__ wkb,
            unsigned short* __restrict__ wvb, unsigned short* __restrict__ wob) {
  constexpr int W4 = 1024 * 1024 / 4;   // 262,144 float4 units per weight
  const int i = blockIdx.x * 256 + threadIdx.x;
  const int r = i / W4;
  const int off = i - r * W4;
  const float* src = (r == 0) ? wq : (r == 1) ? wk : (r == 2) ? wv : wo;
  unsigned short* dst = (r == 0) ? wqb : (r == 1) ? wkb : (r == 2) ? wvb : wob;
  const float4 f = ((const float4*)src)[off];
  ushort4 o;
  o.x = f2bf(f.x); o.y = f2bf(f.y); o.z = f2bf(f.z); o.w = f2bf(f.w);
  ((ushort4*)dst)[off] = o;
}

// ---------------- merged Q/K/V projection GEMM (one launch, 1536 blocks) ----------------
// which = blockIdx.x>>9 selects {0:Q(scale), 1:K, 2:V(transposed store)}.
// Per-512-group: flat XCD-chunked decode (R11). K-loop: BK=64, A staged
// fp32->reg->cvt_pk->ds_write (R12/R14, verified). Epilogue branches runtime.
__global__ __launch_bounds__(256)
void gemm_qkv(const float* __restrict__ Aq, const float* __restrict__ Ak,
              const float* __restrict__ Av,
              const unsigned short* __restrict__ Wq, const unsigned short* __restrict__ Wk,
              const unsigned short* __restrict__ Wv,
              const float* __restrict__ bq, const float* __restrict__ bk,
              const float* __restrict__ bv,
              unsigned short* __restrict__ Qp, unsigned short* __restrict__ Kp,
              unsigned short* __restrict__ Vt,
              int M, int N, int K) {
  __shared__ unsigned short As[128 * 64];
  __shared__ unsigned short Bs[128 * 64];
  const int which = blockIdx.x >> 9;           // 0..2
  const int bid = blockIdx.x & 511;
  const float* Af = (which == 0) ? Aq : (which == 1) ? Ak : Av;
  const unsigned short* Bw = (which == 0) ? Wq : (which == 1) ? Wk : Wv;
  const float* bias = (which == 0) ? bq : (which == 1) ? bk : bv;

  const int tid = threadIdx.x;
  const int lane = tid & 63;
  const int w = tid >> 6;
  const int wm = (w >> 1) * 64;
  const int wn = (w & 1) * 64;
  const int xcd = bid & 7, jj = bid >> 3;
  const int m0 = (xcd * 8 + (jj >> 3)) * 128;
  const int n0 = (jj & 7) * 128;
  const int l15 = lane & 15, l4 = lane >> 4;

  f32x4 acc[4][4] = {};

  for (int k0 = 0; k0 < K; k0 += 64) {
    // issue fp32 A loads BEFORE the barrier (no LDS hazard; latency hidden)
    float4 av[4][2];
#pragma unroll
    for (int q = 0; q < 4; ++q) {
      const int c = q * 256 + tid;
      const int row = c >> 3, kc = (c & 7) * 8;
      const float4* ap = (const float4*)(Af + (size_t)(m0 + row) * K + k0 + kc);
      av[q][0] = ap[0];
      av[q][1] = ap[1];
    }
    __syncthreads();  // previous tile's LDS reads done
#pragma unroll
    for (int q = 0; q < 4; ++q) {
      const int c = q * 256 + tid;
      union { bf16x8 v; unsigned u[4]; } p;
      p.u[0] = cvtpk_bf16(av[q][0].x, av[q][0].y);
      p.u[1] = cvtpk_bf16(av[q][0].z, av[q][0].w);
      p.u[2] = cvtpk_bf16(av[q][1].x, av[q][1].y);
      p.u[3] = cvtpk_bf16(av[q][1].z, av[q][1].w);
      *(bf16x8*)&As[c * 8] = p.v;
    }
#pragma unroll
    for (int q = 0; q < 4; ++q) {
      const int c = q * 256 + tid;
      const int row = c >> 3, kc = (c & 7) * 8;
      gld16(&Bs[c * 8], &Bw[(size_t)(n0 + row) * K + k0 + kc]);
    }
    __syncthreads();  // publish A writes; drain B gld

#pragma unroll
    for (int kk = 0; kk < 2; ++kk) {
      bf16x8 af[4], bfr[4];
#pragma unroll
      for (int m = 0; m < 4; ++m)
        af[m] = *(const bf16x8*)&As[(wm + m * 16 + l15) * 64 + kk * 32 + l4 * 8];
#pragma unroll
      for (int n = 0; n < 4; ++n)
        bfr[n] = *(const bf16x8*)&Bs[(wn + n * 16 + l15) * 64 + kk * 32 + l4 * 8];
#pragma unroll
      for (int m = 0; m < 4; ++m)
#pragma unroll
        for (int n = 0; n < 4; ++n)
          acc[m][n] = __builtin_amdgcn_mfma_f32_16x16x32_bf16(af[m], bfr[n], acc[m][n], 0, 0, 0);
    }
  }

  const int crow = l4 * 4;
#pragma unroll
  for (int m = 0; m < 4; ++m) {
#pragma unroll
    for (int n = 0; n < 4; ++n) {
      const int col = n0 + wn + n * 16 + l15;
      const float bv_ = bias[col];
      if (which == 2) {
        // V: write transposed Vt[(b*16+h)*64+d][s], 4 consecutive s per 8B store
        constexpr int SS = 2048;
        const int rowb = m0 + wm + m * 16 + crow;      // multiple of 4
        const int b_ = rowb >> 11, s_ = rowb & (SS - 1);
        const int vrow = ((b_ << 4) + (col >> 6)) * 64 + (col & 63);
        uint2 pk;
        pk.x = cvtpk_bf16(acc[m][n][0] + bv_, acc[m][n][1] + bv_);
        pk.y = cvtpk_bf16(acc[m][n][2] + bv_, acc[m][n][3] + bv_);
        *(uint2*)&Vt[(size_t)vrow * SS + s_] = pk;
      } else {
        unsigned short* Cb = (which == 0) ? Qp : Kp;
        const float sc = (which == 0) ? 0.125f * 1.44269504f : 1.0f;
#pragma unroll
        for (int j = 0; j < 4; ++j) {
          const int row = m0 + wm + m * 16 + crow + j;
          Cb[(size_t)row * N + col] = f2bf((acc[m][n][j] + bv_) * sc);
        }
      }
    }
  }
}

// ---------------- output projection GEMM (bf16 A via gld16, fp32 out) ----------------
__global__ __launch_bounds__(256)
void gemm_out(const unsigned short* __restrict__ Ab,
              const unsigned short* __restrict__ Bw,
              const float* __restrict__ bias,
              float* __restrict__ Cf,
              int M, int N, int K) {
  __shared__ unsigned short As[128 * 64];
  __shared__ unsigned short Bs[128 * 64];
  const int tid = threadIdx.x;
  const int lane = tid & 63;
  const int w = tid >> 6;
  const int wm = (w >> 1) * 64;
  const int wn = (w & 1) * 64;
  const int bid = blockIdx.x;
  const int xcd = bid & 7, jj = bid >> 3;
  const int m0 = (xcd * 8 + (jj >> 3)) * 128;
  const int n0 = (jj & 7) * 128;
  const int l15 = lane & 15, l4 = lane >> 4;

  f32x4 acc[4][4] = {};

  for (int k0 = 0; k0 < K; k0 += 64) {
    __syncthreads();
#pragma unroll
    for (int q = 0; q < 4; ++q) {
      const int c = q * 256 + tid;
      const int row = c >> 3, kc = (c & 7) * 8;
      gld16(&As[c * 8], &Ab[(size_t)(m0 + row) * K + k0 + kc]);
      gld16(&Bs[c * 8], &Bw[(size_t)(n0 + row) * K + k0 + kc]);
    }
    __syncthreads();

#pragma unroll
    for (int kk = 0; kk < 2; ++kk) {
      bf16x8 af[4], bfr[4];
#pragma unroll
      for (int m = 0; m < 4; ++m)
        af[m] = *(const bf16x8*)&As[(wm + m * 16 + l15) * 64 + kk * 32 + l4 * 8];
#pragma unroll
      for (int n = 0; n < 4; ++n)
        bfr[n] = *(const bf16x8*)&Bs[(wn + n * 16 + l15) * 64 + kk * 32 + l4 * 8];
#pragma unroll
      for (int m = 0; m < 4; ++m)
#pragma unroll
        for (int n = 0; n < 4; ++n)
          acc[m][n] = __builtin_amdgcn_mfma_f32_16x16x32_bf16(af[m], bfr[n], acc[m][n], 0, 0, 0);
    }
  }

  const int crow = l4 * 4;
#pragma unroll
  for (int m = 0; m < 4; ++m) {
#pragma unroll
    for (int n = 0; n < 4; ++n) {
      const int col = n0 + wn + n * 16 + l15;
      const float bv_ = bias[col];
#pragma unroll
      for (int j = 0; j < 4; ++j) {
        const int row = m0 + wm + m * 16 + crow + j;
        Cf[(size_t)row * N + col] = acc[m][n][j] + bv_;
      }
    }
  }
}

// ---------------- flash attention, causal, cooperative 4-wave blocks ----------------
// FROZEN structure (= R6/R10-R14, passed six times). ONLY change: s_setprio
// hints around the two MFMA clusters (T5) — no math/address/sync change.
__global__ __launch_bounds__(256)
void attn_fwd32b(const unsigned short* __restrict__ Qp,   // [B*S,1024] bf16 (scaled)
                 const unsigned short* __restrict__ Kp,   // [B*S,1024] bf16
                 const unsigned short* __restrict__ Vt,   // [(b*16+h)*64+d, S] bf16
                 unsigned short* __restrict__ Xo) {       // [B*S,1024] bf16
  constexpr int S = 2048, Dm = 1024;
  const int bh = blockIdx.x & 63;
  const int g  = 15 - (int)(blockIdx.x >> 6);   // longest blocks first
  const int b = bh >> 4, h = bh & 15;
  const int w = threadIdx.x >> 6;
  const int lane = threadIdx.x & 63;
  const int l31 = lane & 31, hi = lane >> 5;
  const int qb = 4 * g + w;
  const int qrow = qb * 32 + l31;
  const int ntw = qb + 1;          // this wave's KV tiles; tile ntw-1 masked
  const int NT = 4 * g + 4;        // uniform block trip count (even)

  // Q B-frags: col=q=l31, k(d)=c*16+hi*8
  const unsigned short* qptr = Qp + (size_t)(b * S + qrow) * Dm + h * 64 + hi * 8;
  bf16x8 qf[4];
#pragma unroll
  for (int c = 0; c < 4; ++c) qf[c] = *(const bf16x8*)(qptr + c * 16);

  const unsigned short* kbase = Kp + (size_t)(b * S) * Dm + h * 64 + hi * 8;
  const unsigned short* vr0 = Vt + (size_t)(bh * 64 + l31) * S + hi * 8;
  const unsigned short* vr1 = vr0 + (size_t)32 * S;

  f32x16 ot0 = {}, ot1 = {};   // O^T: rows d (0-31 / 32-63), col q=l31
  float m = -1e30f, l = 0.f;

  auto loadK = [&](bf16x8 (&kr)[4], int t) {
    const unsigned short* krow = kbase + (size_t)(t * 32 + l31) * Dm;
#pragma unroll
    for (int c = 0; c < 4; ++c) kr[c] = *(const bf16x8*)(krow + c * 16);
  };

  auto body = [&](bf16x8 (&kr)[4], int t) {
    const int kv0 = t * 32;
    // V loads issued early; consumed after softmax
    const bf16x8 vf0a = *(const bf16x8*)(vr0 + kv0);
    const bf16x8 vf0b = *(const bf16x8*)(vr0 + kv0 + 16);
    const bf16x8 vf1a = *(const bf16x8*)(vr1 + kv0);
    const bf16x8 vf1b = *(const bf16x8*)(vr1 + kv0 + 16);
    // S^T = K · Q  (rows kv, col q)
    f32x16 ts = {};
    __builtin_amdgcn_s_setprio(1);
#pragma unroll
    for (int c = 0; c < 4; ++c) ts = mfma32(kr[c], qf[c], ts);
    __builtin_amdgcn_s_setprio(0);
    if (t == ntw - 1) {   // diagonal tile
#pragma unroll
      for (int r = 0; r < 16; ++r) {
        const int kvp = kv0 + (r & 3) + 8 * (r >> 2) + 4 * hi;
        if (kvp > qrow) ts[r] = -1e9f;
      }
    }
    // row max: lane-local + 1 cross-half shfl
    float pmax = ts[0];
#pragma unroll
    for (int r = 1; r < 16; ++r) pmax = fmaxf(pmax, ts[r]);
    pmax = fmaxf(pmax, __shfl_xor(pmax, 32));
    // deferred rescale (T13; log2 units)
    if (__any(pmax > m + 11.5f)) {
      const float mn = (pmax > m + 11.5f) ? pmax : m;
      const float fct = __builtin_amdgcn_exp2f(m - mn);
      m = mn; l *= fct;
#pragma unroll
      for (int r = 0; r < 16; ++r) { ot0[r] *= fct; ot1[r] *= fct; }
    }
    // p = 2^(s-m), row-sum
    float p[16], ls = 0.f;
#pragma unroll
    for (int r = 0; r < 16; ++r) {
      p[r] = __builtin_amdgcn_exp2f(ts[r] - m);
      ls += p[r];
    }
    ls += __shfl_xor(ls, 32);
    l += ls;
    // pack bf16 pairs + cross-half exchange -> P^T B-frags (k=kv)
    unsigned ua[8];
#pragma unroll
    for (int i = 0; i < 8; ++i) ua[i] = cvtpk_bf16(p[2 * i], p[2 * i + 1]);
    union FR { bf16x8 v; unsigned u[4]; } fr0, fr1;
    {
      unsigned sa = hi ? ua[0] : ua[2], sb = hi ? ua[1] : ua[3];
      unsigned xa = __shfl_xor(sa, 32), xb = __shfl_xor(sb, 32);
      fr0.u[0] = hi ? xa : ua[0]; fr0.u[1] = hi ? xb : ua[1];
      fr0.u[2] = hi ? ua[2] : xa; fr0.u[3] = hi ? ua[3] : xb;
      unsigned sc = hi ? ua[4] : ua[6], sd = hi ? ua[5] : ua[7];
      unsigned xc = __shfl_xor(sc, 32), xd = __shfl_xor(sd, 32);
      fr1.u[0] = hi ? xc : ua[4]; fr1.u[1] = hi ? xd : ua[5];
      fr1.u[2] = hi ? ua[6] : xc; fr1.u[3] = hi ? ua[7] : xd;
    }
    // O^T += V^T · P^T
    __builtin_amdgcn_s_setprio(1);
    ot0 = mfma32(vf0a, fr0.v, ot0);
    ot0 = mfma32(vf0b, fr1.v, ot0);
    ot1 = mfma32(vf1a, fr0.v, ot1);
    ot1 = mfma32(vf1b, fr1.v, ot1);
    __builtin_amdgcn_s_setprio(0);
  };

  // ping-pong K prefetch; identical loads across the 4 waves (L1-shared).
  bf16x8 kA[4], kB[4];
  loadK(kA, 0);
  for (int t = 0; t < NT; t += 2) {
    loadK(kB, t + 1);
    if (t < ntw) body(kA, t);
    __builtin_amdgcn_s_barrier();
    const int t2 = (t + 2 < NT) ? (t + 2) : (NT - 1);  // clamped (redundant on last)
    loadK(kA, t2);
    if (t + 1 < ntw) body(kB, t + 1);
    __builtin_amdgcn_s_barrier();
  }

  // epilogue: normalize (lane-local l), pack pairs, 8B stores
  const float inv = 1.f / l;
  unsigned short* orow = Xo + (size_t)(b * S + qrow) * Dm + h * 64;
#pragma unroll
  for (int rq = 0; rq < 4; ++rq) {
    uint2 pr;
    pr.x = cvtpk_bf16(ot0[4 * rq + 0] * inv, ot0[4 * rq + 1] * inv);
    pr.y = cvtpk_bf16(ot0[4 * rq + 2] * inv, ot0[4 * rq + 3] * inv);
    *(uint2*)(orow + 8 * rq + 4 * hi) = pr;
    uint2 pr1;
    pr1.x = cvtpk_bf16(ot1[4 * rq + 0] * inv, ot1[4 * rq + 1] * inv);
    pr1.y = cvtpk_bf16(ot1[4 * rq + 2] * inv, ot1[4 * rq + 3] * inv);
    *(uint2*)(orow + 32 + 8 * rq + 4 * hi) = pr1;
  }
}

// ---------------- launch ----------------
extern "C" void kernel_launch(void* const* d_in, const int* in_sizes, int n_in,
                              void* d_out, int out_size, void* d_ws, size_t ws_size,
                              hipStream_t stream) {
  const float* query = (const float*)d_in[0];
  const float* key   = (const float*)d_in[1];
  const float* value = (const float*)d_in[2];
  const float* Wq = (const float*)d_in[4];
  const float* bq = (const float*)d_in[5];
  const float* Wk = (const float*)d_in[6];
  const float* bk = (const float*)d_in[7];
  const float* Wv = (const float*)d_in[8];
  const float* bv = (const float*)d_in[9];
  const float* Wo = (const float*)d_in[10];
  const float* bo = (const float*)d_in[11];

  constexpr int B = 4, S = 2048, D = 1024;
  constexpr int M = B * S;
  const size_t MB = 1024u * 1024u;
  uint8_t* ws = (uint8_t*)d_ws;

  unsigned short* Wqb = (unsigned short*)(ws + 48 * MB);
  unsigned short* Wkb = (unsigned short*)(ws + 50 * MB);
  unsigned short* Wvb = (unsigned short*)(ws + 52 * MB);
  unsigned short* Wob = (unsigned short*)(ws + 54 * MB);
  unsigned short* Qp  = (unsigned short*)(ws + 56 * MB);
  unsigned short* Kp  = (unsigned short*)(ws + 72 * MB);
  unsigned short* Vt  = (unsigned short*)(ws + 32 * MB);
  unsigned short* Xat = (unsigned short*)(ws + 16 * MB);

  // weights-only cast: 4*W4 float4 units
  constexpr int W4 = D * D / 4;
  cast_w<<<4 * W4 / 256, 256, 0, stream>>>(Wq, Wk, Wv, Wo, Wqb, Wkb, Wvb, Wob);

  // merged Q/K/V projections: one 1536-block launch
  gemm_qkv<<<1536, 256, 0, stream>>>(query, key, value, Wqb, Wkb, Wvb,
                                     bq, bk, bv, Qp, Kp, Vt, M, D, D);

  attn_fwd32b<<<1024, 256, 0, stream>>>(Qp, Kp, Vt, Xat);

  // output projection: A already bf16, fp32 out
  gemm_out<<<512, 256, 0, stream>>>(Xat, Wob, bo, (float*)d_out, M, D, D);
}